// Round 9
// baseline (2709.575 us; speedup 1.0000x reference)
//
#include <hip/hip_runtime.h>
#include <hip/hip_fp16.h>

// TGCN 2-layer, T=12, F=8, H=64, N=50k, E=800k.
// R9: quad-wave gathers (4 nodes/wave, 4ch/lane, uint2/uint4 rows -> half the
// VMEM instructions per edge) + degree-sorted node permutation (counting sort,
// 64 bins) so each wave-quad has uniform degree (wave-uniform edge loop).
// Dense MFMA structure and Aglob-reuse algorithm unchanged from R8.

#define FT 96
#define TSTEPS 12

typedef _Float16 f16x8 __attribute__((ext_vector_type(8)));
typedef float f32x4 __attribute__((ext_vector_type(4)));

static __device__ __forceinline__ float lo2f(unsigned v) {
    __half2 h2 = *reinterpret_cast<const __half2*>(&v);
    return __low2float(h2);
}
static __device__ __forceinline__ float hi2f(unsigned v) {
    __half2 h2 = *reinterpret_cast<const __half2*>(&v);
    return __high2float(h2);
}
static __device__ __forceinline__ float wof(unsigned p) {
    return __half2float(__ushort_as_half((unsigned short)(p >> 16)));
}
static __device__ __forceinline__ unsigned packh2(float a, float b) {
    __half2 h = __floats2half2_rn(a, b);
    return *reinterpret_cast<unsigned*>(&h);
}

// ---------------- CSR build ----------------
__global__ void hist_k(const int* __restrict__ dst, int* __restrict__ deg, int E) {
    int e = blockIdx.x * blockDim.x + threadIdx.x;
    if (e < E) atomicAdd(&deg[dst[e]], 1);
}

__global__ __launch_bounds__(256) void partial_k(const int* __restrict__ deg,
                                                 int* __restrict__ part, int N) {
    __shared__ int sm[256];
    int i = blockIdx.x * 256 + threadIdx.x;
    sm[threadIdx.x] = (i < N) ? deg[i] : 0;
    __syncthreads();
    for (int off = 128; off > 0; off >>= 1) {
        if (threadIdx.x < off) sm[threadIdx.x] += sm[threadIdx.x + off];
        __syncthreads();
    }
    if (threadIdx.x == 0) part[blockIdx.x] = sm[0];
}

__global__ __launch_bounds__(256) void scanpart_k(int* __restrict__ part,
                                                  int* __restrict__ rowptr,
                                                  int G, int N) {
    __shared__ int sm[256];
    int v = (threadIdx.x < G) ? part[threadIdx.x] : 0;
    sm[threadIdx.x] = v;
    __syncthreads();
    for (int off = 1; off < 256; off <<= 1) {
        int t = (threadIdx.x >= (unsigned)off) ? sm[threadIdx.x - off] : 0;
        __syncthreads();
        sm[threadIdx.x] += t;
        __syncthreads();
    }
    if (threadIdx.x < G) part[threadIdx.x] = sm[threadIdx.x] - v;
    if (threadIdx.x == 255) rowptr[N] = sm[255];
}

__global__ __launch_bounds__(256) void scanchunk_k(const int* __restrict__ deg,
                                                   const int* __restrict__ part,
                                                   int* __restrict__ rowptr,
                                                   int* __restrict__ cursor, int N) {
    __shared__ int sm[256];
    int i = blockIdx.x * 256 + threadIdx.x;
    int v = (i < N) ? deg[i] : 0;
    sm[threadIdx.x] = v;
    __syncthreads();
    for (int off = 1; off < 256; off <<= 1) {
        int t = (threadIdx.x >= (unsigned)off) ? sm[threadIdx.x - off] : 0;
        __syncthreads();
        sm[threadIdx.x] += t;
        __syncthreads();
    }
    int excl = sm[threadIdx.x] - v + part[blockIdx.x];
    if (i < N) { rowptr[i] = excl; cursor[i] = excl; }
}

__global__ void fill_k(const int* __restrict__ src, const int* __restrict__ dst,
                       const float* __restrict__ ew, int* __restrict__ cursor,
                       unsigned* __restrict__ csr_ew, int E) {
    int e = blockIdx.x * blockDim.x + threadIdx.x;
    if (e >= E) return;
    int pos = atomicAdd(&cursor[dst[e]], 1);
    unsigned hw = (unsigned)__half_as_ushort(__float2half(ew[e]));
    csr_ew[pos] = (unsigned)src[e] | (hw << 16);
}

// ---------------- degree-sorted permutation ----------------
__global__ void deghist_k(const int* __restrict__ deg, int* __restrict__ bins, int N) {
    int n = blockIdx.x * blockDim.x + threadIdx.x;
    if (n < N) { int d = deg[n]; atomicAdd(&bins[d > 63 ? 63 : d], 1); }
}
__global__ void binscan_k(int* __restrict__ bins) {
    if (threadIdx.x == 0) {
        int acc = 0;
        for (int i = 0; i < 64; ++i) { int v = bins[i]; bins[i] = acc; acc += v; }
    }
}
__global__ void permfill_k(const int* __restrict__ deg, int* __restrict__ bins,
                           int* __restrict__ perm, int N) {
    int n = blockIdx.x * blockDim.x + threadIdx.x;
    if (n < N) {
        int d = deg[n];
        int pos = atomicAdd(&bins[d > 63 ? 63 : d], 1);
        perm[pos] = n;
    }
}

__global__ void x2h_k(const float* __restrict__ x, _Float16* __restrict__ xh, int M) {
    int i = blockIdx.x * blockDim.x + threadIdx.x;
    if (i < M) xh[i] = (_Float16)x[i];
}

// weight prep: fp16 transposed [C][K] layouts
__global__ void wprep_k(const float* __restrict__ Wg0, const float* __restrict__ Wc0,
                        const float* __restrict__ Wg1, const float* __restrict__ Wc1,
                        _Float16* __restrict__ Wg1t, _Float16* __restrict__ Wc1t,
                        _Float16* __restrict__ Wc0t, _Float16* __restrict__ Wg0t_h,
                        _Float16* __restrict__ Wg0t_x) {
    int i = blockIdx.x * 256 + threadIdx.x;
    if (i < 128 * 128) { int c = i >> 7, k = i & 127; Wg1t[i] = (_Float16)Wg1[k * 128 + c]; }
    if (i < 64 * 128)  { int c = i >> 7, k = i & 127; Wc1t[i] = (_Float16)Wc1[k * 64 + c]; }
    if (i < 64 * 96)   { int c = i / 96, k = i - c * 96;
                         Wc0t[i] = (k < 72) ? (_Float16)Wc0[k * 64 + c] : (_Float16)0.f; }
    if (i < 128 * 64)  { int c = i >> 6, k = i & 63; Wg0t_h[i] = (_Float16)Wg0[(8 + k) * 128 + c]; }
    if (i < 128 * 32)  { int c = i >> 5, k = i & 31;
                         Wg0t_x[i] = (k < 8) ? (_Float16)Wg0[k * 128 + c] : (_Float16)0.f; }
}

// gather of xh (96 fp16 ch/node), writes transposed aggXt[t][n][f]
__global__ __launch_bounds__(256) void gather96_k(
    const _Float16* __restrict__ xh, const int* __restrict__ rowptr,
    const unsigned* __restrict__ csr_ew, float* __restrict__ aggXt, int N) {
    int n = blockIdx.x * 4 + (threadIdx.x >> 6);
    if (n >= N) return;
    int c = threadIdx.x & 63;
    int beg = rowptr[n], end = rowptr[n + 1];
    int deg = end - beg;
    float a0 = 0.f, a1 = 0.f;
    unsigned ev = 0;
    if (c < deg) ev = csr_ew[beg + c];
    int m = deg < 64 ? deg : 64;
    int m8 = (m + 7) & ~7;
#pragma unroll 8
    for (int j = 0; j < m8; ++j) {
        unsigned p = __shfl(ev, j);
        int s = p & 0xffff;
        float w = wof(p);
        const _Float16* row = xh + (size_t)s * FT;
        a0 = fmaf(w, (float)row[c], a0);
        if (c < 32) a1 = fmaf(w, (float)row[64 + c], a1);
    }
    for (int e = beg + 64; e < end; ++e) {
        unsigned p = csr_ew[e];
        int s = p & 0xffff;
        float w = wof(p);
        const _Float16* row = xh + (size_t)s * FT;
        a0 = fmaf(w, (float)row[c], a0);
        if (c < 32) a1 = fmaf(w, (float)row[64 + c], a1);
    }
    { int f = c / 12, tt = c - f * 12;
      aggXt[((size_t)tt * N + n) * 8 + f] = a0; }
    if (c < 32) { int cc = 64 + c; int f = cc / 12, tt = cc - f * 12;
      aggXt[((size_t)tt * N + n) * 8 + f] = a1; }
}

// t=0 gate0 (h0=0): only z0 needed (r0*h0 = 0)
__global__ void g0z_k(const float* __restrict__ aggXt, const float* __restrict__ Wg0,
                      const float* __restrict__ bg0, _Float16* __restrict__ Zh, int N) {
    int i = blockIdx.x * blockDim.x + threadIdx.x;
    int n = i >> 6;
    if (n >= N) return;
    int c = i & 63;
    float acc = bg0[64 + c];
#pragma unroll
    for (int f = 0; f < 8; ++f) acc += aggXt[(size_t)n * 8 + f] * Wg0[f * 128 + 64 + c];
    Zh[(size_t)n * 64 + c] = (_Float16)(1.f / (1.f + __expf(-acc)));
}

// ---------------- quad-wave gather, single fp16 table (rows 128B) ----------
// wave = 4 nodes (quarters of 16 lanes); lane covers channels 4c4..4c4+3.
__device__ __forceinline__ void gquad1(const uint2* __restrict__ f2,
    const unsigned* __restrict__ csr_ew, int beg, int deg, int c4, int lb,
    float& a0, float& a1, float& a2, float& a3) {
    int m = deg < 32 ? deg : 32;
    unsigned ev0 = 0, ev1 = 0;
    if (c4 < m) ev0 = csr_ew[beg + c4];
    if (16 + c4 < m) ev1 = csr_ew[beg + 16 + c4];
    int dm = deg;
    dm = max(dm, __shfl_xor(dm, 16));
    dm = max(dm, __shfl_xor(dm, 32));
    int jm = dm < 32 ? dm : 32;
    jm = (jm + 15) & ~15;
    a0 = a1 = a2 = a3 = 0.f;
    for (int j0 = 0; j0 < jm; j0 += 16) {
        unsigned e = j0 ? ev1 : ev0;
        uint2 vv[16]; float ww[16];
#pragma unroll
        for (int k = 0; k < 16; ++k) {
            unsigned p = __shfl(e, lb + k);
            ww[k] = wof(p);
            vv[k] = f2[(size_t)(p & 0xffff) * 16 + c4];
        }
#pragma unroll
        for (int k = 0; k < 16; ++k) {
            a0 = fmaf(ww[k], lo2f(vv[k].x), a0);
            a1 = fmaf(ww[k], hi2f(vv[k].x), a1);
            a2 = fmaf(ww[k], lo2f(vv[k].y), a2);
            a3 = fmaf(ww[k], hi2f(vv[k].y), a3);
        }
    }
    int end = beg + deg;
    for (int e = beg + 32; e < end; ++e) {
        unsigned p = csr_ew[e];
        float w = wof(p);
        uint2 v = f2[(size_t)(p & 0xffff) * 16 + c4];
        a0 = fmaf(w, lo2f(v.x), a0);
        a1 = fmaf(w, hi2f(v.x), a1);
        a2 = fmaf(w, lo2f(v.y), a2);
        a3 = fmaf(w, hi2f(v.y), a3);
    }
}

// ---------------- layer-0 cand (512 thr, quad gather + MFMA) ----------------
__global__ __launch_bounds__(512) void l0_cand(
    const _Float16* __restrict__ RH0h, const float* __restrict__ aggXt, int t,
    const int* __restrict__ rowptr, const unsigned* __restrict__ csr_ew,
    const int* __restrict__ perm,
    const _Float16* __restrict__ Wc0t, const float* __restrict__ bc,
    const _Float16* __restrict__ Zh, float* __restrict__ h0f,
    unsigned* __restrict__ h01, int N) {
    __shared__ _Float16 sA[64 * 104];
    const int tid = threadIdx.x;
    const int lane = tid & 63;
    const int wid = __builtin_amdgcn_readfirstlane(tid >> 6);
    const int nb = blockIdx.x * 64;
    // zero pad cols 72..103
    { int nl = tid >> 3, k0 = 72 + ((tid & 7) << 2);
#pragma unroll
      for (int q = 0; q < 4; ++q) sA[nl * 104 + k0 + q] = (_Float16)0.f; }
    // aggX fill cols 0..7
    { int nl = tid >> 3, f = tid & 7, gi = nb + nl;
      int n = (gi < N) ? perm[gi] : -1;
      sA[nl * 104 + f] = (n >= 0) ? (_Float16)aggXt[((size_t)t * N + n) * 8 + f] : (_Float16)0.f; }
    // quad gather cols 8..71
    const int c4 = lane & 15, lb = lane & 48, q = lane >> 4;
    const uint2* f2 = (const uint2*)RH0h;
    for (int it = 0; it < 2; ++it) {
        int nl = (wid * 2 + it) * 4 + q;
        int gi = nb + nl;
        int beg = 0, deg = 0;
        if (gi < N) { int n = perm[gi]; beg = rowptr[n]; deg = rowptr[n + 1] - beg; }
        float a0, a1, a2, a3;
        gquad1(f2, csr_ew, beg, deg, c4, lb, a0, a1, a2, a3);
        uint2 u; u.x = packh2(a0, a1); u.y = packh2(a2, a3);
        *(uint2*)&sA[nl * 104 + 8 + 4 * c4] = u;
    }
    __syncthreads();
    // dense: out[64][64] = sA @ Wc0t^T (K=96), tanh
    const int ln15 = lane & 15, quad = lane >> 4;
    const int mt = wid & 3, ng = wid >> 2;
    const int mrow = mt * 16 + ln15;
    f16x8 afr[3];
#pragma unroll
    for (int kc = 0; kc < 3; ++kc)
        afr[kc] = *(const f16x8*)&sA[mrow * 104 + kc * 32 + quad * 8];
    f32x4 acc[2];
    int cols[2];
#pragma unroll
    for (int nt = 0; nt < 2; ++nt) {
        int col = (ng * 2 + nt) * 16 + ln15;
        cols[nt] = col;
        float b = bc[col];
        f32x4 a = {b, b, b, b};
#pragma unroll
        for (int kc = 0; kc < 3; ++kc) {
            f16x8 bfr = *(const f16x8*)&Wc0t[(size_t)col * 96 + kc * 32 + quad * 8];
            a = __builtin_amdgcn_mfma_f32_16x16x32_f16(afr[kc], bfr, a, 0, 0, 0);
        }
        acc[nt] = a;
    }
    __syncthreads();
#pragma unroll
    for (int nt = 0; nt < 2; ++nt) {
#pragma unroll
        for (int r = 0; r < 4; ++r) {
            float e = __expf(2.f * acc[nt][r]);
            float c = 1.f - 2.f / (e + 1.f);
            int row = mt * 16 + quad * 4 + r;
            sA[row * 104 + cols[nt]] = (_Float16)c;
        }
    }
    __syncthreads();
    for (int i = tid; i < 4096; i += 512) {
        int nl = i >> 6, cc = i & 63, gi = nb + nl;
        if (gi < N) {
            int n = perm[gi];
            size_t idx = (size_t)n * 64 + cc;
            float z = (float)Zh[idx];
            float hv = h0f[idx];
            float nh = z * hv + (1.f - z) * (float)sA[nl * 104 + cc];
            h0f[idx] = nh;
            reinterpret_cast<__half*>(h01)[idx * 2] = __float2half(nh);
        }
    }
}

// ---------------- layer-1 gate (512 thr, quad dual gather + MFMA) ----------
__global__ __launch_bounds__(512) void l1_gate(
    const unsigned* __restrict__ h01, const float* __restrict__ h1f,
    const int* __restrict__ rowptr, const unsigned* __restrict__ csr_ew,
    const int* __restrict__ perm,
    const _Float16* __restrict__ Wg1t, const float* __restrict__ bg,
    unsigned* __restrict__ Aglobh32, _Float16* __restrict__ Zh,
    _Float16* __restrict__ RH1h, int N) {
    __shared__ _Float16 sA[64 * 136];
    const int tid = threadIdx.x;
    const int lane = tid & 63;
    const int wid = __builtin_amdgcn_readfirstlane(tid >> 6);
    const int nb = blockIdx.x * 64;
    const int c4 = lane & 15, lb = lane & 48, q = lane >> 4;
    const uint4* __restrict__ f4 = (const uint4*)h01;
    for (int it = 0; it < 2; ++it) {
        int nl = (wid * 2 + it) * 4 + q;
        int gi = nb + nl;
        int beg = 0, deg = 0;
        if (gi < N) { int n = perm[gi]; beg = rowptr[n]; deg = rowptr[n + 1] - beg; }
        int m = deg < 32 ? deg : 32;
        unsigned ev0 = 0, ev1 = 0;
        if (c4 < m) ev0 = csr_ew[beg + c4];
        if (16 + c4 < m) ev1 = csr_ew[beg + 16 + c4];
        int dm = deg;
        dm = max(dm, __shfl_xor(dm, 16));
        dm = max(dm, __shfl_xor(dm, 32));
        int jm = dm < 32 ? dm : 32;
        jm = (jm + 7) & ~7;
        float b0 = 0.f, b1 = 0.f, b2 = 0.f, b3 = 0.f;   // h0 channels
        float c0 = 0.f, c1 = 0.f, c2 = 0.f, c3 = 0.f;   // h1 channels
        for (int j0 = 0; j0 < jm; j0 += 8) {
            unsigned e = (j0 < 16) ? ev0 : ev1;
            int bs = j0 & 15;
            uint4 vv[8]; float ww[8];
#pragma unroll
            for (int k = 0; k < 8; ++k) {
                unsigned p = __shfl(e, lb + bs + k);
                ww[k] = wof(p);
                vv[k] = f4[(size_t)(p & 0xffff) * 16 + c4];
            }
#pragma unroll
            for (int k = 0; k < 8; ++k) {
                b0 = fmaf(ww[k], lo2f(vv[k].x), b0); c0 = fmaf(ww[k], hi2f(vv[k].x), c0);
                b1 = fmaf(ww[k], lo2f(vv[k].y), b1); c1 = fmaf(ww[k], hi2f(vv[k].y), c1);
                b2 = fmaf(ww[k], lo2f(vv[k].z), b2); c2 = fmaf(ww[k], hi2f(vv[k].z), c2);
                b3 = fmaf(ww[k], lo2f(vv[k].w), b3); c3 = fmaf(ww[k], hi2f(vv[k].w), c3);
            }
        }
        int end = beg + deg;
        for (int e = beg + 32; e < end; ++e) {
            unsigned p = csr_ew[e];
            float w = wof(p);
            uint4 v = f4[(size_t)(p & 0xffff) * 16 + c4];
            b0 = fmaf(w, lo2f(v.x), b0); c0 = fmaf(w, hi2f(v.x), c0);
            b1 = fmaf(w, lo2f(v.y), b1); c1 = fmaf(w, hi2f(v.y), c1);
            b2 = fmaf(w, lo2f(v.z), b2); c2 = fmaf(w, hi2f(v.z), c2);
            b3 = fmaf(w, lo2f(v.w), b3); c3 = fmaf(w, hi2f(v.w), c3);
        }
        uint2 u0; u0.x = packh2(b0, b1); u0.y = packh2(b2, b3);
        uint2 u1; u1.x = packh2(c0, c1); u1.y = packh2(c2, c3);
        *(uint2*)&sA[nl * 136 + 4 * c4] = u0;
        *(uint2*)&sA[nl * 136 + 64 + 4 * c4] = u1;
    }
    __syncthreads();
    // Aglob dump (fp16 packed u32 view) — sA cols 0..63
    for (int i = tid; i < 2048; i += 512) {
        int nl = i >> 5, c2 = i & 31, gi = nb + nl;
        if (gi < N) Aglobh32[(size_t)perm[gi] * 32 + c2] = ((const unsigned*)sA)[nl * 68 + c2];
    }
    // dense: rz[64][128] = sA @ Wg1t^T (K=128), sigmoid
    const int ln15 = lane & 15, quad = lane >> 4;
    const int mt = wid & 3, ng = wid >> 2;
    const int mrow = mt * 16 + ln15;
    f16x8 afr[4];
#pragma unroll
    for (int kc = 0; kc < 4; ++kc)
        afr[kc] = *(const f16x8*)&sA[mrow * 136 + kc * 32 + quad * 8];
    f32x4 acc[4];
    int cols[4];
#pragma unroll
    for (int nt = 0; nt < 4; ++nt) {
        int col = (ng * 4 + nt) * 16 + ln15;
        cols[nt] = col;
        float b = bg[col];
        f32x4 a = {b, b, b, b};
#pragma unroll
        for (int kc = 0; kc < 4; ++kc) {
            f16x8 bfr = *(const f16x8*)&Wg1t[(size_t)col * 128 + kc * 32 + quad * 8];
            a = __builtin_amdgcn_mfma_f32_16x16x32_f16(afr[kc], bfr, a, 0, 0, 0);
        }
        acc[nt] = a;
    }
    __syncthreads();
#pragma unroll
    for (int nt = 0; nt < 4; ++nt) {
#pragma unroll
        for (int r = 0; r < 4; ++r) {
            float s = 1.f / (1.f + __expf(-acc[nt][r]));
            int row = mt * 16 + quad * 4 + r;
            sA[row * 136 + cols[nt]] = (_Float16)s;
        }
    }
    __syncthreads();
    for (int i = tid; i < 4096; i += 512) {
        int nl = i >> 6, cc = i & 63, gi = nb + nl;
        if (gi < N) {
            size_t idx = (size_t)perm[gi] * 64 + cc;
            float r = (float)sA[nl * 136 + cc];
            float z = (float)sA[nl * 136 + 64 + cc];
            RH1h[idx] = (_Float16)(r * h1f[idx]);
            Zh[idx] = (_Float16)z;
        }
    }
}

// ---------------- layer-1 cand + fused gate0(t+1) (512 thr, MFMA) ----------
__global__ __launch_bounds__(512) void l1_cand_fused(
    const _Float16* __restrict__ RH1h, const unsigned* __restrict__ Aglobh32,
    const float* __restrict__ aggXt, int tn, int do_gate, int final,
    const int* __restrict__ rowptr, const unsigned* __restrict__ csr_ew,
    const int* __restrict__ perm,
    const _Float16* __restrict__ Wc1t, const float* __restrict__ bc1,
    const _Float16* __restrict__ Wg0t_h, const _Float16* __restrict__ Wg0t_x,
    const float* __restrict__ bg0, const float* __restrict__ h0f,
    _Float16* __restrict__ Zh, _Float16* __restrict__ RH0h,
    float* __restrict__ h1f, unsigned* __restrict__ h01,
    const float* __restrict__ Wout, const float* __restrict__ bout,
    float* __restrict__ out, int N) {
    __shared__ _Float16 sA[64 * 136];
    __shared__ _Float16 sX[64 * 40];
    const int tid = threadIdx.x;
    const int lane = tid & 63;
    const int wid = __builtin_amdgcn_readfirstlane(tid >> 6);
    const int nb = blockIdx.x * 64;
    // sX zero (cols 8..39) + aggX fill (cols 0..7)
    { int nl = tid >> 3, k0 = 8 + ((tid & 7) << 2);
#pragma unroll
      for (int q = 0; q < 4; ++q) sX[nl * 40 + k0 + q] = (_Float16)0.f; }
    if (do_gate) {
        int nl = tid >> 3, f = tid & 7, gi = nb + nl;
        int n = (gi < N) ? perm[gi] : -1;
        sX[nl * 40 + f] = (n >= 0) ? (_Float16)aggXt[((size_t)tn * N + n) * 8 + f] : (_Float16)0.f;
    }
    // Aglobh -> sA cols 0..63 (u32 packed)
    for (int i = tid; i < 2048; i += 512) {
        int nl = i >> 5, c2 = i & 31, gi = nb + nl;
        ((unsigned*)sA)[nl * 68 + c2] = (gi < N) ? Aglobh32[(size_t)perm[gi] * 32 + c2] : 0u;
    }
    // quad gather gconv(RH1) -> sA cols 64..127
    const int c4 = lane & 15, lb = lane & 48, q = lane >> 4;
    const uint2* f2 = (const uint2*)RH1h;
    for (int it = 0; it < 2; ++it) {
        int nl = (wid * 2 + it) * 4 + q;
        int gi = nb + nl;
        int beg = 0, deg = 0;
        if (gi < N) { int n = perm[gi]; beg = rowptr[n]; deg = rowptr[n + 1] - beg; }
        float a0, a1, a2, a3;
        gquad1(f2, csr_ew, beg, deg, c4, lb, a0, a1, a2, a3);
        uint2 u; u.x = packh2(a0, a1); u.y = packh2(a2, a3);
        *(uint2*)&sA[nl * 136 + 64 + 4 * c4] = u;
    }
    __syncthreads();
    const int ln15 = lane & 15, quad = lane >> 4;
    const int mt = wid & 3, ng = wid >> 2;
    const int mrow = mt * 16 + ln15;
    f16x8 afr[4];
#pragma unroll
    for (int kc = 0; kc < 4; ++kc)
        afr[kc] = *(const f16x8*)&sA[mrow * 136 + kc * 32 + quad * 8];
    // cand: c1[64][64] = sA @ Wc1t^T (K=128), 2 N-tiles/wave
    f32x4 accc[2];
    int colc[2];
#pragma unroll
    for (int nt = 0; nt < 2; ++nt) {
        int col = (ng * 2 + nt) * 16 + ln15;
        colc[nt] = col;
        float b = bc1[col];
        f32x4 a = {b, b, b, b};
#pragma unroll
        for (int kc = 0; kc < 4; ++kc) {
            f16x8 bfr = *(const f16x8*)&Wc1t[(size_t)col * 128 + kc * 32 + quad * 8];
            a = __builtin_amdgcn_mfma_f32_16x16x32_f16(afr[kc], bfr, a, 0, 0, 0);
        }
        accc[nt] = a;
    }
    // gate0(t+1): rz0[64][128] = sX@Wg0t_x + sA(0:64)@Wg0t_h, 4 N-tiles/wave
    f32x4 accg[4];
    int colg[4];
    if (do_gate) {
        f16x8 xfr = *(const f16x8*)&sX[mrow * 40 + quad * 8];
#pragma unroll
        for (int nt = 0; nt < 4; ++nt) {
            int col = (ng * 4 + nt) * 16 + ln15;
            colg[nt] = col;
            float b = bg0[col];
            f32x4 a = {b, b, b, b};
            f16x8 bx = *(const f16x8*)&Wg0t_x[(size_t)col * 32 + quad * 8];
            a = __builtin_amdgcn_mfma_f32_16x16x32_f16(xfr, bx, a, 0, 0, 0);
#pragma unroll
            for (int kc = 0; kc < 2; ++kc) {
                f16x8 bfr = *(const f16x8*)&Wg0t_h[(size_t)col * 64 + kc * 32 + quad * 8];
                a = __builtin_amdgcn_mfma_f32_16x16x32_f16(afr[kc], bfr, a, 0, 0, 0);
            }
            accg[nt] = a;
        }
    }
    __syncthreads();
    // stage: c1 -> sA cols 64..127; r0 -> sA cols 0..63 (z0 stays in regs)
#pragma unroll
    for (int nt = 0; nt < 2; ++nt) {
#pragma unroll
        for (int r = 0; r < 4; ++r) {
            float e = __expf(2.f * accc[nt][r]);
            float c = 1.f - 2.f / (e + 1.f);
            int row = mt * 16 + quad * 4 + r;
            sA[row * 136 + 64 + colc[nt]] = (_Float16)c;
        }
    }
    if (do_gate) {
#pragma unroll
        for (int nt = 0; nt < 4; ++nt) {
            if (colg[nt] < 64) {
#pragma unroll
                for (int r = 0; r < 4; ++r) {
                    float s = 1.f / (1.f + __expf(-accg[nt][r]));
                    int row = mt * 16 + quad * 4 + r;
                    sA[row * 136 + colg[nt]] = (_Float16)s;
                }
            }
        }
    }
    __syncthreads();
    // epilogue-1: h1 update (+RH0h, +final out)
    for (int i = tid; i < 4096; i += 512) {
        int nl = i >> 6, cc = i & 63, gi = nb + nl;
        float nh = 0.f;
        int n = -1;
        if (gi < N) {
            n = perm[gi];
            size_t idx = (size_t)n * 64 + cc;
            float z1 = (float)Zh[idx];
            float hv = h1f[idx];
            nh = z1 * hv + (1.f - z1) * (float)sA[nl * 136 + 64 + cc];
            if (!final) {
                h1f[idx] = nh;
                reinterpret_cast<__half*>(h01)[idx * 2 + 1] = __float2half(nh);
            }
            if (do_gate) RH0h[idx] = (_Float16)((float)sA[nl * 136 + cc] * h0f[idx]);
        }
        if (final) {
            float p = nh * Wout[cc];
            for (int off = 32; off > 0; off >>= 1) p += __shfl_down(p, off);
            if (cc == 0 && n >= 0) out[n] = p + bout[0];
        }
    }
    if (do_gate) {
        __syncthreads();
        // stage z0 (gate cols >= 64) -> sA cols 0..63
#pragma unroll
        for (int nt = 0; nt < 4; ++nt) {
            if (colg[nt] >= 64) {
#pragma unroll
                for (int r = 0; r < 4; ++r) {
                    float s = 1.f / (1.f + __expf(-accg[nt][r]));
                    int row = mt * 16 + quad * 4 + r;
                    sA[row * 136 + (colg[nt] - 64)] = (_Float16)s;
                }
            }
        }
        __syncthreads();
        for (int i = tid; i < 4096; i += 512) {
            int nl = i >> 6, cc = i & 63, gi = nb + nl;
            if (gi < N) Zh[(size_t)perm[gi] * 64 + cc] = sA[nl * 136 + cc];
        }
    }
}

static inline size_t align16(size_t v) { return (v + 15) & ~(size_t)15; }

extern "C" void kernel_launch(void* const* d_in, const int* in_sizes, int n_in,
                              void* d_out, int out_size, void* d_ws, size_t ws_size,
                              hipStream_t stream) {
    const float* x   = (const float*)d_in[0];
    const int*   ei  = (const int*)d_in[1];
    const float* ew  = (const float*)d_in[2];
    const float* Wg0 = (const float*)d_in[3];
    const float* bg0 = (const float*)d_in[4];
    const float* Wc0 = (const float*)d_in[5];
    const float* bc0 = (const float*)d_in[6];
    const float* Wg1 = (const float*)d_in[7];
    const float* bg1 = (const float*)d_in[8];
    const float* Wc1 = (const float*)d_in[9];
    const float* bc1 = (const float*)d_in[10];
    const float* Wout = (const float*)d_in[11];
    const float* bout = (const float*)d_in[12];

    const int N = in_sizes[0] / FT;
    const int E = in_sizes[2];
    const int* src = ei;
    const int* dst = ei + E;

    char* base = (char*)d_ws;
    size_t off = 0;
    int* deg = (int*)(base + off);            off = align16(off + (size_t)N * 4);
    int* cursor = (int*)(base + off);         off = align16(off + (size_t)N * 4);
    int* rowptr = (int*)(base + off);         off = align16(off + (size_t)(N + 1) * 4);
    int* part = (int*)(base + off);           off = align16(off + 256 * 4);
    int* bins = (int*)(base + off);           off = align16(off + 64 * 4);
    int* perm = (int*)(base + off);           off = align16(off + (size_t)N * 4);
    unsigned* csr_ew = (unsigned*)(base + off);  off = align16(off + (size_t)E * 4);
    float* aggXt = (float*)(base + off);      off = align16(off + (size_t)N * FT * 4);
    float* h0f = (float*)(base + off);        off = align16(off + (size_t)N * 64 * 4);
    float* h1f = (float*)(base + off);        off = align16(off + (size_t)N * 64 * 4);
    unsigned* h01 = (unsigned*)(base + off);  off = align16(off + (size_t)N * 64 * 4);
    unsigned* Aglobh32 = (unsigned*)(base + off); off = align16(off + (size_t)N * 32 * 4);
    _Float16* Zh = (_Float16*)(base + off);   off = align16(off + (size_t)N * 64 * 2);
    _Float16* RH0h = (_Float16*)(base + off); off = align16(off + (size_t)N * 64 * 2);
    _Float16* RH1h = (_Float16*)(base + off); off = align16(off + (size_t)N * 64 * 2);
    _Float16* xh = (_Float16*)(base + off);   off = align16(off + (size_t)N * FT * 2);
    _Float16* Wg1t = (_Float16*)(base + off); off = align16(off + 128 * 128 * 2);
    _Float16* Wc1t = (_Float16*)(base + off); off = align16(off + 64 * 128 * 2);
    _Float16* Wc0t = (_Float16*)(base + off); off = align16(off + 64 * 96 * 2);
    _Float16* Wg0t_h = (_Float16*)(base + off); off = align16(off + 128 * 64 * 2);
    _Float16* Wg0t_x = (_Float16*)(base + off); off = align16(off + 128 * 32 * 2);

    const int gE   = (E + 255) / 256;
    const int gN4  = (N + 3) / 4;
    const int gN64 = (N + 63) / 64;
    const int G    = (N + 255) / 256;
    const int gNn  = (N + 255) / 256;

    hipMemsetAsync(deg, 0, (size_t)N * 4, stream);
    hipMemsetAsync(bins, 0, 64 * 4, stream);
    hipMemsetAsync(h0f, 0, (size_t)N * 64 * 4, stream);
    hipMemsetAsync(h1f, 0, (size_t)N * 64 * 4, stream);
    hipMemsetAsync(h01, 0, (size_t)N * 64 * 4, stream);
    hipMemsetAsync(RH0h, 0, (size_t)N * 64 * 2, stream);

    x2h_k<<<(N * FT + 255) / 256, 256, 0, stream>>>(x, xh, N * FT);
    wprep_k<<<64, 256, 0, stream>>>(Wg0, Wc0, Wg1, Wc1, Wg1t, Wc1t, Wc0t, Wg0t_h, Wg0t_x);
    hist_k<<<gE, 256, 0, stream>>>(dst, deg, E);
    partial_k<<<G, 256, 0, stream>>>(deg, part, N);
    scanpart_k<<<1, 256, 0, stream>>>(part, rowptr, G, N);
    scanchunk_k<<<G, 256, 0, stream>>>(deg, part, rowptr, cursor, N);
    fill_k<<<gE, 256, 0, stream>>>(src, dst, ew, cursor, csr_ew, E);
    // degree-sorted permutation
    deghist_k<<<gNn, 256, 0, stream>>>(deg, bins, N);
    binscan_k<<<1, 64, 0, stream>>>(bins);
    permfill_k<<<gNn, 256, 0, stream>>>(deg, bins, perm, N);
    gather96_k<<<gN4, 256, 0, stream>>>(xh, rowptr, csr_ew, aggXt, N);

    // t=0: h0=0 -> RH0h=0 (memset); z0 from aggX only
    g0z_k<<<(N * 64 + 255) / 256, 256, 0, stream>>>(aggXt, Wg0, bg0, Zh, N);

    for (int t = 0; t < TSTEPS; ++t) {
        l0_cand<<<gN64, 512, 0, stream>>>(RH0h, aggXt, t, rowptr, csr_ew, perm,
                                          Wc0t, bc0, Zh, h0f, h01, N);
        l1_gate<<<gN64, 512, 0, stream>>>(h01, h1f, rowptr, csr_ew, perm,
                                          Wg1t, bg1, Aglobh32, Zh, RH1h, N);
        l1_cand_fused<<<gN64, 512, 0, stream>>>(RH1h, Aglobh32, aggXt, t + 1,
                                                (t + 1 < TSTEPS) ? 1 : 0,
                                                (t + 1 == TSTEPS) ? 1 : 0,
                                                rowptr, csr_ew, perm,
                                                Wc1t, bc1, Wg0t_h, Wg0t_x, bg0,
                                                h0f, Zh, RH0h, h1f, h01,
                                                Wout, bout, (float*)d_out, N);
    }
}

// Round 10
// 2165.235 us; speedup vs baseline: 1.2514x; 1.2514x over previous
//
#include <hip/hip_runtime.h>
#include <hip/hip_fp16.h>

// TGCN 2-layer, T=12, F=8, H=64, N=50k, E=800k.
// R10 = R8 + quad-wave gathers (from R9) WITHOUT the degree permutation.
// R9 post-mortem: perm scattered the epilogue streams (random 256B rows) and
// permfill_k cost 142us of atomic contention -> regression. Quad gather kept:
// 4 nodes/wave, 4ch/lane, uint2/uint4 rows -> ~1.7x fewer VMEM instrs/edge.

#define FT 96
#define TSTEPS 12

typedef _Float16 f16x8 __attribute__((ext_vector_type(8)));
typedef float f32x4 __attribute__((ext_vector_type(4)));

static __device__ __forceinline__ float lo2f(unsigned v) {
    __half2 h2 = *reinterpret_cast<const __half2*>(&v);
    return __low2float(h2);
}
static __device__ __forceinline__ float hi2f(unsigned v) {
    __half2 h2 = *reinterpret_cast<const __half2*>(&v);
    return __high2float(h2);
}
static __device__ __forceinline__ float wof(unsigned p) {
    return __half2float(__ushort_as_half((unsigned short)(p >> 16)));
}
static __device__ __forceinline__ unsigned packh2(float a, float b) {
    __half2 h = __floats2half2_rn(a, b);
    return *reinterpret_cast<unsigned*>(&h);
}

// ---------------- CSR build ----------------
__global__ void hist_k(const int* __restrict__ dst, int* __restrict__ deg, int E) {
    int e = blockIdx.x * blockDim.x + threadIdx.x;
    if (e < E) atomicAdd(&deg[dst[e]], 1);
}

__global__ __launch_bounds__(256) void partial_k(const int* __restrict__ deg,
                                                 int* __restrict__ part, int N) {
    __shared__ int sm[256];
    int i = blockIdx.x * 256 + threadIdx.x;
    sm[threadIdx.x] = (i < N) ? deg[i] : 0;
    __syncthreads();
    for (int off = 128; off > 0; off >>= 1) {
        if (threadIdx.x < off) sm[threadIdx.x] += sm[threadIdx.x + off];
        __syncthreads();
    }
    if (threadIdx.x == 0) part[blockIdx.x] = sm[0];
}

__global__ __launch_bounds__(256) void scanpart_k(int* __restrict__ part,
                                                  int* __restrict__ rowptr,
                                                  int G, int N) {
    __shared__ int sm[256];
    int v = (threadIdx.x < G) ? part[threadIdx.x] : 0;
    sm[threadIdx.x] = v;
    __syncthreads();
    for (int off = 1; off < 256; off <<= 1) {
        int t = (threadIdx.x >= (unsigned)off) ? sm[threadIdx.x - off] : 0;
        __syncthreads();
        sm[threadIdx.x] += t;
        __syncthreads();
    }
    if (threadIdx.x < G) part[threadIdx.x] = sm[threadIdx.x] - v;
    if (threadIdx.x == 255) rowptr[N] = sm[255];
}

__global__ __launch_bounds__(256) void scanchunk_k(const int* __restrict__ deg,
                                                   const int* __restrict__ part,
                                                   int* __restrict__ rowptr,
                                                   int* __restrict__ cursor, int N) {
    __shared__ int sm[256];
    int i = blockIdx.x * 256 + threadIdx.x;
    int v = (i < N) ? deg[i] : 0;
    sm[threadIdx.x] = v;
    __syncthreads();
    for (int off = 1; off < 256; off <<= 1) {
        int t = (threadIdx.x >= (unsigned)off) ? sm[threadIdx.x - off] : 0;
        __syncthreads();
        sm[threadIdx.x] += t;
        __syncthreads();
    }
    int excl = sm[threadIdx.x] - v + part[blockIdx.x];
    if (i < N) { rowptr[i] = excl; cursor[i] = excl; }
}

__global__ void fill_k(const int* __restrict__ src, const int* __restrict__ dst,
                       const float* __restrict__ ew, int* __restrict__ cursor,
                       unsigned* __restrict__ csr_ew, int E) {
    int e = blockIdx.x * blockDim.x + threadIdx.x;
    if (e >= E) return;
    int pos = atomicAdd(&cursor[dst[e]], 1);
    unsigned hw = (unsigned)__half_as_ushort(__float2half(ew[e]));
    csr_ew[pos] = (unsigned)src[e] | (hw << 16);
}

__global__ void x2h_k(const float* __restrict__ x, _Float16* __restrict__ xh, int M) {
    int i = blockIdx.x * blockDim.x + threadIdx.x;
    if (i < M) xh[i] = (_Float16)x[i];
}

// weight prep: fp16 transposed [C][K] layouts
__global__ void wprep_k(const float* __restrict__ Wg0, const float* __restrict__ Wc0,
                        const float* __restrict__ Wg1, const float* __restrict__ Wc1,
                        _Float16* __restrict__ Wg1t, _Float16* __restrict__ Wc1t,
                        _Float16* __restrict__ Wc0t, _Float16* __restrict__ Wg0t_h,
                        _Float16* __restrict__ Wg0t_x) {
    int i = blockIdx.x * 256 + threadIdx.x;
    if (i < 128 * 128) { int c = i >> 7, k = i & 127; Wg1t[i] = (_Float16)Wg1[k * 128 + c]; }
    if (i < 64 * 128)  { int c = i >> 7, k = i & 127; Wc1t[i] = (_Float16)Wc1[k * 64 + c]; }
    if (i < 64 * 96)   { int c = i / 96, k = i - c * 96;
                         Wc0t[i] = (k < 72) ? (_Float16)Wc0[k * 64 + c] : (_Float16)0.f; }
    if (i < 128 * 64)  { int c = i >> 6, k = i & 63; Wg0t_h[i] = (_Float16)Wg0[(8 + k) * 128 + c]; }
    if (i < 128 * 32)  { int c = i >> 5, k = i & 31;
                         Wg0t_x[i] = (k < 8) ? (_Float16)Wg0[k * 128 + c] : (_Float16)0.f; }
}

// gather of xh (96 fp16 ch/node), writes transposed aggXt[t][n][f]
__global__ __launch_bounds__(256) void gather96_k(
    const _Float16* __restrict__ xh, const int* __restrict__ rowptr,
    const unsigned* __restrict__ csr_ew, float* __restrict__ aggXt, int N) {
    int n = blockIdx.x * 4 + (threadIdx.x >> 6);
    if (n >= N) return;
    int c = threadIdx.x & 63;
    int beg = rowptr[n], end = rowptr[n + 1];
    int deg = end - beg;
    float a0 = 0.f, a1 = 0.f;
    unsigned ev = 0;
    if (c < deg) ev = csr_ew[beg + c];
    int m = deg < 64 ? deg : 64;
    int m8 = (m + 7) & ~7;
#pragma unroll 8
    for (int j = 0; j < m8; ++j) {
        unsigned p = __shfl(ev, j);
        int s = p & 0xffff;
        float w = wof(p);
        const _Float16* row = xh + (size_t)s * FT;
        a0 = fmaf(w, (float)row[c], a0);
        if (c < 32) a1 = fmaf(w, (float)row[64 + c], a1);
    }
    for (int e = beg + 64; e < end; ++e) {
        unsigned p = csr_ew[e];
        int s = p & 0xffff;
        float w = wof(p);
        const _Float16* row = xh + (size_t)s * FT;
        a0 = fmaf(w, (float)row[c], a0);
        if (c < 32) a1 = fmaf(w, (float)row[64 + c], a1);
    }
    { int f = c / 12, tt = c - f * 12;
      aggXt[((size_t)tt * N + n) * 8 + f] = a0; }
    if (c < 32) { int cc = 64 + c; int f = cc / 12, tt = cc - f * 12;
      aggXt[((size_t)tt * N + n) * 8 + f] = a1; }
}

// t=0 gate0 (h0=0): only z0 needed (r0*h0 = 0)
__global__ void g0z_k(const float* __restrict__ aggXt, const float* __restrict__ Wg0,
                      const float* __restrict__ bg0, _Float16* __restrict__ Zh, int N) {
    int i = blockIdx.x * blockDim.x + threadIdx.x;
    int n = i >> 6;
    if (n >= N) return;
    int c = i & 63;
    float acc = bg0[64 + c];
#pragma unroll
    for (int f = 0; f < 8; ++f) acc += aggXt[(size_t)n * 8 + f] * Wg0[f * 128 + 64 + c];
    Zh[(size_t)n * 64 + c] = (_Float16)(1.f / (1.f + __expf(-acc)));
}

// ---------------- quad-wave gather, single fp16 table (rows 128B) ----------
// wave = 4 nodes (quarters of 16 lanes); lane covers channels 4c4..4c4+3.
__device__ __forceinline__ void gquad1(const uint2* __restrict__ f2,
    const unsigned* __restrict__ csr_ew, int beg, int deg, int c4, int lb,
    float& a0, float& a1, float& a2, float& a3) {
    int m = deg < 32 ? deg : 32;
    unsigned ev0 = 0, ev1 = 0;
    if (c4 < m) ev0 = csr_ew[beg + c4];
    if (16 + c4 < m) ev1 = csr_ew[beg + 16 + c4];
    int dm = deg;
    dm = max(dm, __shfl_xor(dm, 16));
    dm = max(dm, __shfl_xor(dm, 32));
    int jm = dm < 32 ? dm : 32;
    jm = (jm + 15) & ~15;
    a0 = a1 = a2 = a3 = 0.f;
    for (int j0 = 0; j0 < jm; j0 += 16) {
        unsigned e = j0 ? ev1 : ev0;
        uint2 vv[16]; float ww[16];
#pragma unroll
        for (int k = 0; k < 16; ++k) {
            unsigned p = __shfl(e, lb + k);
            ww[k] = wof(p);
            vv[k] = f2[(size_t)(p & 0xffff) * 16 + c4];
        }
#pragma unroll
        for (int k = 0; k < 16; ++k) {
            a0 = fmaf(ww[k], lo2f(vv[k].x), a0);
            a1 = fmaf(ww[k], hi2f(vv[k].x), a1);
            a2 = fmaf(ww[k], lo2f(vv[k].y), a2);
            a3 = fmaf(ww[k], hi2f(vv[k].y), a3);
        }
    }
    int end = beg + deg;
    for (int e = beg + 32; e < end; ++e) {
        unsigned p = csr_ew[e];
        float w = wof(p);
        uint2 v = f2[(size_t)(p & 0xffff) * 16 + c4];
        a0 = fmaf(w, lo2f(v.x), a0);
        a1 = fmaf(w, hi2f(v.x), a1);
        a2 = fmaf(w, lo2f(v.y), a2);
        a3 = fmaf(w, hi2f(v.y), a3);
    }
}

// ---------------- layer-0 cand (512 thr, quad gather + MFMA) ----------------
__global__ __launch_bounds__(512) void l0_cand(
    const _Float16* __restrict__ RH0h, const float* __restrict__ aggXt, int t,
    const int* __restrict__ rowptr, const unsigned* __restrict__ csr_ew,
    const _Float16* __restrict__ Wc0t, const float* __restrict__ bc,
    const _Float16* __restrict__ Zh, float* __restrict__ h0f,
    unsigned* __restrict__ h01, int N) {
    __shared__ _Float16 sA[64 * 104];
    const int tid = threadIdx.x;
    const int lane = tid & 63;
    const int wid = __builtin_amdgcn_readfirstlane(tid >> 6);
    const int nb = blockIdx.x * 64;
    // zero pad cols 72..103
    { int nl = tid >> 3, k0 = 72 + ((tid & 7) << 2);
#pragma unroll
      for (int q = 0; q < 4; ++q) sA[nl * 104 + k0 + q] = (_Float16)0.f; }
    // aggX fill cols 0..7
    { int nl = tid >> 3, f = tid & 7, n = nb + nl;
      sA[nl * 104 + f] = (n < N) ? (_Float16)aggXt[((size_t)t * N + n) * 8 + f] : (_Float16)0.f; }
    // quad gather cols 8..71
    const int c4 = lane & 15, lb = lane & 48, q = lane >> 4;
    const uint2* f2 = (const uint2*)RH0h;
    for (int it = 0; it < 2; ++it) {
        int nl = (wid * 2 + it) * 4 + q;
        int n = nb + nl;
        int beg = 0, deg = 0;
        if (n < N) { beg = rowptr[n]; deg = rowptr[n + 1] - beg; }
        float a0, a1, a2, a3;
        gquad1(f2, csr_ew, beg, deg, c4, lb, a0, a1, a2, a3);
        uint2 u; u.x = packh2(a0, a1); u.y = packh2(a2, a3);
        *(uint2*)&sA[nl * 104 + 8 + 4 * c4] = u;
    }
    __syncthreads();
    // dense: out[64][64] = sA @ Wc0t^T (K=96), tanh
    const int ln15 = lane & 15, quad = lane >> 4;
    const int mt = wid & 3, ng = wid >> 2;
    const int mrow = mt * 16 + ln15;
    f16x8 afr[3];
#pragma unroll
    for (int kc = 0; kc < 3; ++kc)
        afr[kc] = *(const f16x8*)&sA[mrow * 104 + kc * 32 + quad * 8];
    f32x4 acc[2];
    int cols[2];
#pragma unroll
    for (int nt = 0; nt < 2; ++nt) {
        int col = (ng * 2 + nt) * 16 + ln15;
        cols[nt] = col;
        float b = bc[col];
        f32x4 a = {b, b, b, b};
#pragma unroll
        for (int kc = 0; kc < 3; ++kc) {
            f16x8 bfr = *(const f16x8*)&Wc0t[(size_t)col * 96 + kc * 32 + quad * 8];
            a = __builtin_amdgcn_mfma_f32_16x16x32_f16(afr[kc], bfr, a, 0, 0, 0);
        }
        acc[nt] = a;
    }
    __syncthreads();
#pragma unroll
    for (int nt = 0; nt < 2; ++nt) {
#pragma unroll
        for (int r = 0; r < 4; ++r) {
            float e = __expf(2.f * acc[nt][r]);
            float c = 1.f - 2.f / (e + 1.f);
            int row = mt * 16 + quad * 4 + r;
            sA[row * 104 + cols[nt]] = (_Float16)c;
        }
    }
    __syncthreads();
    for (int i = tid; i < 4096; i += 512) {
        int nl = i >> 6, cc = i & 63, n = nb + nl;
        if (n < N) {
            size_t idx = (size_t)n * 64 + cc;
            float z = (float)Zh[idx];
            float hv = h0f[idx];
            float nh = z * hv + (1.f - z) * (float)sA[nl * 104 + cc];
            h0f[idx] = nh;
            reinterpret_cast<__half*>(h01)[idx * 2] = __float2half(nh);
        }
    }
}

// ---------------- layer-1 gate (512 thr, quad dual gather + MFMA) ----------
__global__ __launch_bounds__(512) void l1_gate(
    const unsigned* __restrict__ h01, const float* __restrict__ h1f,
    const int* __restrict__ rowptr, const unsigned* __restrict__ csr_ew,
    const _Float16* __restrict__ Wg1t, const float* __restrict__ bg,
    unsigned* __restrict__ Aglobh32, _Float16* __restrict__ Zh,
    _Float16* __restrict__ RH1h, int N) {
    __shared__ _Float16 sA[64 * 136];
    const int tid = threadIdx.x;
    const int lane = tid & 63;
    const int wid = __builtin_amdgcn_readfirstlane(tid >> 6);
    const int nb = blockIdx.x * 64;
    const int c4 = lane & 15, lb = lane & 48, q = lane >> 4;
    const uint4* __restrict__ f4 = (const uint4*)h01;
    for (int it = 0; it < 2; ++it) {
        int nl = (wid * 2 + it) * 4 + q;
        int n = nb + nl;
        int beg = 0, deg = 0;
        if (n < N) { beg = rowptr[n]; deg = rowptr[n + 1] - beg; }
        int m = deg < 32 ? deg : 32;
        unsigned ev0 = 0, ev1 = 0;
        if (c4 < m) ev0 = csr_ew[beg + c4];
        if (16 + c4 < m) ev1 = csr_ew[beg + 16 + c4];
        int dm = deg;
        dm = max(dm, __shfl_xor(dm, 16));
        dm = max(dm, __shfl_xor(dm, 32));
        int jm = dm < 32 ? dm : 32;
        jm = (jm + 7) & ~7;
        float b0 = 0.f, b1 = 0.f, b2 = 0.f, b3 = 0.f;   // h0 channels
        float c0 = 0.f, c1 = 0.f, c2 = 0.f, c3 = 0.f;   // h1 channels
        for (int j0 = 0; j0 < jm; j0 += 8) {
            unsigned e = (j0 < 16) ? ev0 : ev1;
            int bs = j0 & 15;
            uint4 vv[8]; float ww[8];
#pragma unroll
            for (int k = 0; k < 8; ++k) {
                unsigned p = __shfl(e, lb + bs + k);
                ww[k] = wof(p);
                vv[k] = f4[(size_t)(p & 0xffff) * 16 + c4];
            }
#pragma unroll
            for (int k = 0; k < 8; ++k) {
                b0 = fmaf(ww[k], lo2f(vv[k].x), b0); c0 = fmaf(ww[k], hi2f(vv[k].x), c0);
                b1 = fmaf(ww[k], lo2f(vv[k].y), b1); c1 = fmaf(ww[k], hi2f(vv[k].y), c1);
                b2 = fmaf(ww[k], lo2f(vv[k].z), b2); c2 = fmaf(ww[k], hi2f(vv[k].z), c2);
                b3 = fmaf(ww[k], lo2f(vv[k].w), b3); c3 = fmaf(ww[k], hi2f(vv[k].w), c3);
            }
        }
        int end = beg + deg;
        for (int e = beg + 32; e < end; ++e) {
            unsigned p = csr_ew[e];
            float w = wof(p);
            uint4 v = f4[(size_t)(p & 0xffff) * 16 + c4];
            b0 = fmaf(w, lo2f(v.x), b0); c0 = fmaf(w, hi2f(v.x), c0);
            b1 = fmaf(w, lo2f(v.y), b1); c1 = fmaf(w, hi2f(v.y), c1);
            b2 = fmaf(w, lo2f(v.z), b2); c2 = fmaf(w, hi2f(v.z), c2);
            b3 = fmaf(w, lo2f(v.w), b3); c3 = fmaf(w, hi2f(v.w), c3);
        }
        uint2 u0; u0.x = packh2(b0, b1); u0.y = packh2(b2, b3);
        uint2 u1; u1.x = packh2(c0, c1); u1.y = packh2(c2, c3);
        *(uint2*)&sA[nl * 136 + 4 * c4] = u0;
        *(uint2*)&sA[nl * 136 + 64 + 4 * c4] = u1;
    }
    __syncthreads();
    // Aglob dump (fp16 packed u32 view) — sA cols 0..63
    for (int i = tid; i < 2048; i += 512) {
        int nl = i >> 5, c2 = i & 31, n = nb + nl;
        if (n < N) Aglobh32[(size_t)n * 32 + c2] = ((const unsigned*)sA)[nl * 68 + c2];
    }
    // dense: rz[64][128] = sA @ Wg1t^T (K=128), sigmoid
    const int ln15 = lane & 15, quad = lane >> 4;
    const int mt = wid & 3, ng = wid >> 2;
    const int mrow = mt * 16 + ln15;
    f16x8 afr[4];
#pragma unroll
    for (int kc = 0; kc < 4; ++kc)
        afr[kc] = *(const f16x8*)&sA[mrow * 136 + kc * 32 + quad * 8];
    f32x4 acc[4];
    int cols[4];
#pragma unroll
    for (int nt = 0; nt < 4; ++nt) {
        int col = (ng * 4 + nt) * 16 + ln15;
        cols[nt] = col;
        float b = bg[col];
        f32x4 a = {b, b, b, b};
#pragma unroll
        for (int kc = 0; kc < 4; ++kc) {
            f16x8 bfr = *(const f16x8*)&Wg1t[(size_t)col * 128 + kc * 32 + quad * 8];
            a = __builtin_amdgcn_mfma_f32_16x16x32_f16(afr[kc], bfr, a, 0, 0, 0);
        }
        acc[nt] = a;
    }
    __syncthreads();
#pragma unroll
    for (int nt = 0; nt < 4; ++nt) {
#pragma unroll
        for (int r = 0; r < 4; ++r) {
            float s = 1.f / (1.f + __expf(-acc[nt][r]));
            int row = mt * 16 + quad * 4 + r;
            sA[row * 136 + cols[nt]] = (_Float16)s;
        }
    }
    __syncthreads();
    for (int i = tid; i < 4096; i += 512) {
        int nl = i >> 6, cc = i & 63, n = nb + nl;
        if (n < N) {
            size_t idx = (size_t)n * 64 + cc;
            float r = (float)sA[nl * 136 + cc];
            float z = (float)sA[nl * 136 + 64 + cc];
            RH1h[idx] = (_Float16)(r * h1f[idx]);
            Zh[idx] = (_Float16)z;
        }
    }
}

// ---------------- layer-1 cand + fused gate0(t+1) (512 thr, MFMA) ----------
__global__ __launch_bounds__(512) void l1_cand_fused(
    const _Float16* __restrict__ RH1h, const unsigned* __restrict__ Aglobh32,
    const float* __restrict__ aggXt, int tn, int do_gate, int final,
    const int* __restrict__ rowptr, const unsigned* __restrict__ csr_ew,
    const _Float16* __restrict__ Wc1t, const float* __restrict__ bc1,
    const _Float16* __restrict__ Wg0t_h, const _Float16* __restrict__ Wg0t_x,
    const float* __restrict__ bg0, const float* __restrict__ h0f,
    _Float16* __restrict__ Zh, _Float16* __restrict__ RH0h,
    float* __restrict__ h1f, unsigned* __restrict__ h01,
    const float* __restrict__ Wout, const float* __restrict__ bout,
    float* __restrict__ out, int N) {
    __shared__ _Float16 sA[64 * 136];
    __shared__ _Float16 sX[64 * 40];
    const int tid = threadIdx.x;
    const int lane = tid & 63;
    const int wid = __builtin_amdgcn_readfirstlane(tid >> 6);
    const int nb = blockIdx.x * 64;
    // sX zero (cols 8..39) + aggX fill (cols 0..7)
    { int nl = tid >> 3, k0 = 8 + ((tid & 7) << 2);
#pragma unroll
      for (int q = 0; q < 4; ++q) sX[nl * 40 + k0 + q] = (_Float16)0.f; }
    if (do_gate) {
        int nl = tid >> 3, f = tid & 7, n = nb + nl;
        sX[nl * 40 + f] = (n < N) ? (_Float16)aggXt[((size_t)tn * N + n) * 8 + f] : (_Float16)0.f;
    }
    // Aglobh -> sA cols 0..63 (u32 packed)
    for (int i = tid; i < 2048; i += 512) {
        int nl = i >> 5, c2 = i & 31, n = nb + nl;
        ((unsigned*)sA)[nl * 68 + c2] = (n < N) ? Aglobh32[(size_t)n * 32 + c2] : 0u;
    }
    // quad gather gconv(RH1) -> sA cols 64..127
    const int c4 = lane & 15, lb = lane & 48, q = lane >> 4;
    const uint2* f2 = (const uint2*)RH1h;
    for (int it = 0; it < 2; ++it) {
        int nl = (wid * 2 + it) * 4 + q;
        int n = nb + nl;
        int beg = 0, deg = 0;
        if (n < N) { beg = rowptr[n]; deg = rowptr[n + 1] - beg; }
        float a0, a1, a2, a3;
        gquad1(f2, csr_ew, beg, deg, c4, lb, a0, a1, a2, a3);
        uint2 u; u.x = packh2(a0, a1); u.y = packh2(a2, a3);
        *(uint2*)&sA[nl * 136 + 64 + 4 * c4] = u;
    }
    __syncthreads();
    const int ln15 = lane & 15, quad = lane >> 4;
    const int mt = wid & 3, ng = wid >> 2;
    const int mrow = mt * 16 + ln15;
    f16x8 afr[4];
#pragma unroll
    for (int kc = 0; kc < 4; ++kc)
        afr[kc] = *(const f16x8*)&sA[mrow * 136 + kc * 32 + quad * 8];
    // cand: c1[64][64] = sA @ Wc1t^T (K=128), 2 N-tiles/wave
    f32x4 accc[2];
    int colc[2];
#pragma unroll
    for (int nt = 0; nt < 2; ++nt) {
        int col = (ng * 2 + nt) * 16 + ln15;
        colc[nt] = col;
        float b = bc1[col];
        f32x4 a = {b, b, b, b};
#pragma unroll
        for (int kc = 0; kc < 4; ++kc) {
            f16x8 bfr = *(const f16x8*)&Wc1t[(size_t)col * 128 + kc * 32 + quad * 8];
            a = __builtin_amdgcn_mfma_f32_16x16x32_f16(afr[kc], bfr, a, 0, 0, 0);
        }
        accc[nt] = a;
    }
    // gate0(t+1): rz0[64][128] = sX@Wg0t_x + sA(0:64)@Wg0t_h, 4 N-tiles/wave
    f32x4 accg[4];
    int colg[4];
    if (do_gate) {
        f16x8 xfr = *(const f16x8*)&sX[mrow * 40 + quad * 8];
#pragma unroll
        for (int nt = 0; nt < 4; ++nt) {
            int col = (ng * 4 + nt) * 16 + ln15;
            colg[nt] = col;
            float b = bg0[col];
            f32x4 a = {b, b, b, b};
            f16x8 bx = *(const f16x8*)&Wg0t_x[(size_t)col * 32 + quad * 8];
            a = __builtin_amdgcn_mfma_f32_16x16x32_f16(xfr, bx, a, 0, 0, 0);
#pragma unroll
            for (int kc = 0; kc < 2; ++kc) {
                f16x8 bfr = *(const f16x8*)&Wg0t_h[(size_t)col * 64 + kc * 32 + quad * 8];
                a = __builtin_amdgcn_mfma_f32_16x16x32_f16(afr[kc], bfr, a, 0, 0, 0);
            }
            accg[nt] = a;
        }
    }
    __syncthreads();
    // stage: c1 -> sA cols 64..127; r0 -> sA cols 0..63 (z0 stays in regs)
#pragma unroll
    for (int nt = 0; nt < 2; ++nt) {
#pragma unroll
        for (int r = 0; r < 4; ++r) {
            float e = __expf(2.f * accc[nt][r]);
            float c = 1.f - 2.f / (e + 1.f);
            int row = mt * 16 + quad * 4 + r;
            sA[row * 136 + 64 + colc[nt]] = (_Float16)c;
        }
    }
    if (do_gate) {
#pragma unroll
        for (int nt = 0; nt < 4; ++nt) {
            if (colg[nt] < 64) {
#pragma unroll
                for (int r = 0; r < 4; ++r) {
                    float s = 1.f / (1.f + __expf(-accg[nt][r]));
                    int row = mt * 16 + quad * 4 + r;
                    sA[row * 136 + colg[nt]] = (_Float16)s;
                }
            }
        }
    }
    __syncthreads();
    // epilogue-1: h1 update (+RH0h, +final out)
    for (int i = tid; i < 4096; i += 512) {
        int nl = i >> 6, cc = i & 63, n = nb + nl;
        float nh = 0.f;
        if (n < N) {
            size_t idx = (size_t)n * 64 + cc;
            float z1 = (float)Zh[idx];
            float hv = h1f[idx];
            nh = z1 * hv + (1.f - z1) * (float)sA[nl * 136 + 64 + cc];
            if (!final) {
                h1f[idx] = nh;
                reinterpret_cast<__half*>(h01)[idx * 2 + 1] = __float2half(nh);
            }
            if (do_gate) RH0h[idx] = (_Float16)((float)sA[nl * 136 + cc] * h0f[idx]);
        }
        if (final) {
            float p = nh * Wout[cc];
            for (int off = 32; off > 0; off >>= 1) p += __shfl_down(p, off);
            if (cc == 0 && n < N) out[n] = p + bout[0];
        }
    }
    if (do_gate) {
        __syncthreads();
        // stage z0 (gate cols >= 64) -> sA cols 0..63
#pragma unroll
        for (int nt = 0; nt < 4; ++nt) {
            if (colg[nt] >= 64) {
#pragma unroll
                for (int r = 0; r < 4; ++r) {
                    float s = 1.f / (1.f + __expf(-accg[nt][r]));
                    int row = mt * 16 + quad * 4 + r;
                    sA[row * 136 + (colg[nt] - 64)] = (_Float16)s;
                }
            }
        }
        __syncthreads();
        for (int i = tid; i < 4096; i += 512) {
            int nl = i >> 6, cc = i & 63, n = nb + nl;
            if (n < N) Zh[(size_t)n * 64 + cc] = sA[nl * 136 + cc];
        }
    }
}

static inline size_t align16(size_t v) { return (v + 15) & ~(size_t)15; }

extern "C" void kernel_launch(void* const* d_in, const int* in_sizes, int n_in,
                              void* d_out, int out_size, void* d_ws, size_t ws_size,
                              hipStream_t stream) {
    const float* x   = (const float*)d_in[0];
    const int*   ei  = (const int*)d_in[1];
    const float* ew  = (const float*)d_in[2];
    const float* Wg0 = (const float*)d_in[3];
    const float* bg0 = (const float*)d_in[4];
    const float* Wc0 = (const float*)d_in[5];
    const float* bc0 = (const float*)d_in[6];
    const float* Wg1 = (const float*)d_in[7];
    const float* bg1 = (const float*)d_in[8];
    const float* Wc1 = (const float*)d_in[9];
    const float* bc1 = (const float*)d_in[10];
    const float* Wout = (const float*)d_in[11];
    const float* bout = (const float*)d_in[12];

    const int N = in_sizes[0] / FT;
    const int E = in_sizes[2];
    const int* src = ei;
    const int* dst = ei + E;

    char* base = (char*)d_ws;
    size_t off = 0;
    int* deg = (int*)(base + off);            off = align16(off + (size_t)N * 4);
    int* cursor = (int*)(base + off);         off = align16(off + (size_t)N * 4);
    int* rowptr = (int*)(base + off);         off = align16(off + (size_t)(N + 1) * 4);
    int* part = (int*)(base + off);           off = align16(off + 256 * 4);
    unsigned* csr_ew = (unsigned*)(base + off);  off = align16(off + (size_t)E * 4);
    float* aggXt = (float*)(base + off);      off = align16(off + (size_t)N * FT * 4);
    float* h0f = (float*)(base + off);        off = align16(off + (size_t)N * 64 * 4);
    float* h1f = (float*)(base + off);        off = align16(off + (size_t)N * 64 * 4);
    unsigned* h01 = (unsigned*)(base + off);  off = align16(off + (size_t)N * 64 * 4);
    unsigned* Aglobh32 = (unsigned*)(base + off); off = align16(off + (size_t)N * 32 * 4);
    _Float16* Zh = (_Float16*)(base + off);   off = align16(off + (size_t)N * 64 * 2);
    _Float16* RH0h = (_Float16*)(base + off); off = align16(off + (size_t)N * 64 * 2);
    _Float16* RH1h = (_Float16*)(base + off); off = align16(off + (size_t)N * 64 * 2);
    _Float16* xh = (_Float16*)(base + off);   off = align16(off + (size_t)N * FT * 2);
    _Float16* Wg1t = (_Float16*)(base + off); off = align16(off + 128 * 128 * 2);
    _Float16* Wc1t = (_Float16*)(base + off); off = align16(off + 64 * 128 * 2);
    _Float16* Wc0t = (_Float16*)(base + off); off = align16(off + 64 * 96 * 2);
    _Float16* Wg0t_h = (_Float16*)(base + off); off = align16(off + 128 * 64 * 2);
    _Float16* Wg0t_x = (_Float16*)(base + off); off = align16(off + 128 * 32 * 2);

    const int gE   = (E + 255) / 256;
    const int gN4  = (N + 3) / 4;
    const int gN64 = (N + 63) / 64;
    const int G    = (N + 255) / 256;

    hipMemsetAsync(deg, 0, (size_t)N * 4, stream);
    hipMemsetAsync(h0f, 0, (size_t)N * 64 * 4, stream);
    hipMemsetAsync(h1f, 0, (size_t)N * 64 * 4, stream);
    hipMemsetAsync(h01, 0, (size_t)N * 64 * 4, stream);
    hipMemsetAsync(RH0h, 0, (size_t)N * 64 * 2, stream);

    x2h_k<<<(N * FT + 255) / 256, 256, 0, stream>>>(x, xh, N * FT);
    wprep_k<<<64, 256, 0, stream>>>(Wg0, Wc0, Wg1, Wc1, Wg1t, Wc1t, Wc0t, Wg0t_h, Wg0t_x);
    hist_k<<<gE, 256, 0, stream>>>(dst, deg, E);
    partial_k<<<G, 256, 0, stream>>>(deg, part, N);
    scanpart_k<<<1, 256, 0, stream>>>(part, rowptr, G, N);
    scanchunk_k<<<G, 256, 0, stream>>>(deg, part, rowptr, cursor, N);
    fill_k<<<gE, 256, 0, stream>>>(src, dst, ew, cursor, csr_ew, E);
    gather96_k<<<gN4, 256, 0, stream>>>(xh, rowptr, csr_ew, aggXt, N);

    // t=0: h0=0 -> RH0h=0 (memset); z0 from aggX only
    g0z_k<<<(N * 64 + 255) / 256, 256, 0, stream>>>(aggXt, Wg0, bg0, Zh, N);

    for (int t = 0; t < TSTEPS; ++t) {
        l0_cand<<<gN64, 512, 0, stream>>>(RH0h, aggXt, t, rowptr, csr_ew,
                                          Wc0t, bc0, Zh, h0f, h01, N);
        l1_gate<<<gN64, 512, 0, stream>>>(h01, h1f, rowptr, csr_ew,
                                          Wg1t, bg1, Aglobh32, Zh, RH1h, N);
        l1_cand_fused<<<gN64, 512, 0, stream>>>(RH1h, Aglobh32, aggXt, t + 1,
                                                (t + 1 < TSTEPS) ? 1 : 0,
                                                (t + 1 == TSTEPS) ? 1 : 0,
                                                rowptr, csr_ew,
                                                Wc1t, bc1, Wg0t_h, Wg0t_x, bg0,
                                                h0f, Zh, RH0h, h1f, h01,
                                                Wout, bout, (float*)d_out, N);
    }
}

// Round 11
// 1951.232 us; speedup vs baseline: 1.3886x; 1.1097x over previous
//
#include <hip/hip_runtime.h>
#include <hip/hip_fp16.h>

// TGCN 2-layer, T=12, F=8, H=64, N=50k, E=800k.
// R11 = R8 (best verified: 1965us) + one isolated fix: gpair16 edge-loop
// padding granularity 16 -> 8 (avg slots 26.8 -> 21.6 for max-of-2
// Poisson(16) degrees). Padded slots add exact zeros -> bitwise identical.
// R9/R10 post-mortem: quad-wave gathers lose to pair (max-of-4 padding waste);
// degree permutation scatters epilogue streams. Both abandoned.

#define FT 96
#define TSTEPS 12

typedef _Float16 f16x8 __attribute__((ext_vector_type(8)));
typedef float f32x4 __attribute__((ext_vector_type(4)));

static __device__ __forceinline__ float lo2f(unsigned v) {
    __half2 h2 = *reinterpret_cast<const __half2*>(&v);
    return __low2float(h2);
}
static __device__ __forceinline__ float hi2f(unsigned v) {
    __half2 h2 = *reinterpret_cast<const __half2*>(&v);
    return __high2float(h2);
}
static __device__ __forceinline__ float wof(unsigned p) {
    return __half2float(__ushort_as_half((unsigned short)(p >> 16)));
}

// ---------------- CSR build ----------------
__global__ void hist_k(const int* __restrict__ dst, int* __restrict__ deg, int E) {
    int e = blockIdx.x * blockDim.x + threadIdx.x;
    if (e < E) atomicAdd(&deg[dst[e]], 1);
}

__global__ __launch_bounds__(256) void partial_k(const int* __restrict__ deg,
                                                 int* __restrict__ part, int N) {
    __shared__ int sm[256];
    int i = blockIdx.x * 256 + threadIdx.x;
    sm[threadIdx.x] = (i < N) ? deg[i] : 0;
    __syncthreads();
    for (int off = 128; off > 0; off >>= 1) {
        if (threadIdx.x < off) sm[threadIdx.x] += sm[threadIdx.x + off];
        __syncthreads();
    }
    if (threadIdx.x == 0) part[blockIdx.x] = sm[0];
}

__global__ __launch_bounds__(256) void scanpart_k(int* __restrict__ part,
                                                  int* __restrict__ rowptr,
                                                  int G, int N) {
    __shared__ int sm[256];
    int v = (threadIdx.x < G) ? part[threadIdx.x] : 0;
    sm[threadIdx.x] = v;
    __syncthreads();
    for (int off = 1; off < 256; off <<= 1) {
        int t = (threadIdx.x >= (unsigned)off) ? sm[threadIdx.x - off] : 0;
        __syncthreads();
        sm[threadIdx.x] += t;
        __syncthreads();
    }
    if (threadIdx.x < G) part[threadIdx.x] = sm[threadIdx.x] - v;
    if (threadIdx.x == 255) rowptr[N] = sm[255];
}

__global__ __launch_bounds__(256) void scanchunk_k(const int* __restrict__ deg,
                                                   const int* __restrict__ part,
                                                   int* __restrict__ rowptr,
                                                   int* __restrict__ cursor, int N) {
    __shared__ int sm[256];
    int i = blockIdx.x * 256 + threadIdx.x;
    int v = (i < N) ? deg[i] : 0;
    sm[threadIdx.x] = v;
    __syncthreads();
    for (int off = 1; off < 256; off <<= 1) {
        int t = (threadIdx.x >= (unsigned)off) ? sm[threadIdx.x - off] : 0;
        __syncthreads();
        sm[threadIdx.x] += t;
        __syncthreads();
    }
    int excl = sm[threadIdx.x] - v + part[blockIdx.x];
    if (i < N) { rowptr[i] = excl; cursor[i] = excl; }
}

__global__ void fill_k(const int* __restrict__ src, const int* __restrict__ dst,
                       const float* __restrict__ ew, int* __restrict__ cursor,
                       unsigned* __restrict__ csr_ew, int E) {
    int e = blockIdx.x * blockDim.x + threadIdx.x;
    if (e >= E) return;
    int pos = atomicAdd(&cursor[dst[e]], 1);
    unsigned hw = (unsigned)__half_as_ushort(__float2half(ew[e]));
    csr_ew[pos] = (unsigned)src[e] | (hw << 16);
}

__global__ void x2h_k(const float* __restrict__ x, _Float16* __restrict__ xh, int M) {
    int i = blockIdx.x * blockDim.x + threadIdx.x;
    if (i < M) xh[i] = (_Float16)x[i];
}

// weight prep: fp16 transposed [C][K] layouts
__global__ void wprep_k(const float* __restrict__ Wg0, const float* __restrict__ Wc0,
                        const float* __restrict__ Wg1, const float* __restrict__ Wc1,
                        _Float16* __restrict__ Wg1t, _Float16* __restrict__ Wc1t,
                        _Float16* __restrict__ Wc0t, _Float16* __restrict__ Wg0t_h,
                        _Float16* __restrict__ Wg0t_x) {
    int i = blockIdx.x * 256 + threadIdx.x;
    if (i < 128 * 128) { int c = i >> 7, k = i & 127; Wg1t[i] = (_Float16)Wg1[k * 128 + c]; }
    if (i < 64 * 128)  { int c = i >> 7, k = i & 127; Wc1t[i] = (_Float16)Wc1[k * 64 + c]; }
    if (i < 64 * 96)   { int c = i / 96, k = i - c * 96;
                         Wc0t[i] = (k < 72) ? (_Float16)Wc0[k * 64 + c] : (_Float16)0.f; }
    if (i < 128 * 64)  { int c = i >> 6, k = i & 63; Wg0t_h[i] = (_Float16)Wg0[(8 + k) * 128 + c]; }
    if (i < 128 * 32)  { int c = i >> 5, k = i & 31;
                         Wg0t_x[i] = (k < 8) ? (_Float16)Wg0[k * 128 + c] : (_Float16)0.f; }
}

// gather of xh (96 fp16 ch/node), writes transposed aggXt[t][n][f]
__global__ __launch_bounds__(256) void gather96_k(
    const _Float16* __restrict__ xh, const int* __restrict__ rowptr,
    const unsigned* __restrict__ csr_ew, float* __restrict__ aggXt, int N) {
    int n = blockIdx.x * 4 + (threadIdx.x >> 6);
    if (n >= N) return;
    int c = threadIdx.x & 63;
    int beg = rowptr[n], end = rowptr[n + 1];
    int deg = end - beg;
    float a0 = 0.f, a1 = 0.f;
    unsigned ev = 0;
    if (c < deg) ev = csr_ew[beg + c];
    int m = deg < 64 ? deg : 64;
    int m8 = (m + 7) & ~7;
#pragma unroll 8
    for (int j = 0; j < m8; ++j) {
        unsigned p = __shfl(ev, j);
        int s = p & 0xffff;
        float w = wof(p);
        const _Float16* row = xh + (size_t)s * FT;
        a0 = fmaf(w, (float)row[c], a0);
        if (c < 32) a1 = fmaf(w, (float)row[64 + c], a1);
    }
    for (int e = beg + 64; e < end; ++e) {
        unsigned p = csr_ew[e];
        int s = p & 0xffff;
        float w = wof(p);
        const _Float16* row = xh + (size_t)s * FT;
        a0 = fmaf(w, (float)row[c], a0);
        if (c < 32) a1 = fmaf(w, (float)row[64 + c], a1);
    }
    { int f = c / 12, tt = c - f * 12;
      aggXt[((size_t)tt * N + n) * 8 + f] = a0; }
    if (c < 32) { int cc = 64 + c; int f = cc / 12, tt = cc - f * 12;
      aggXt[((size_t)tt * N + n) * 8 + f] = a1; }
}

// t=0 gate0 (h0=0): only z0 needed (r0*h0 = 0)
__global__ void g0z_k(const float* __restrict__ aggXt, const float* __restrict__ Wg0,
                      const float* __restrict__ bg0, _Float16* __restrict__ Zh, int N) {
    int i = blockIdx.x * blockDim.x + threadIdx.x;
    int n = i >> 6;
    if (n >= N) return;
    int c = i & 63;
    float acc = bg0[64 + c];
#pragma unroll
    for (int f = 0; f < 8; ++f) acc += aggXt[(size_t)n * 8 + f] * Wg0[f * 128 + 64 + c];
    Zh[(size_t)n * 64 + c] = (_Float16)(1.f / (1.f + __expf(-acc)));
}

// pair-wave gather: lanes 0-31 node A, 32-63 node B; lane = channels 2c2,2c2+1
// R11: 8-granularity padding (was 16) — fewer wasted zero-weight slots.
__device__ __forceinline__ void gpair16(const unsigned* __restrict__ feat32,
    const unsigned* __restrict__ csr_ew,
    int begA, int degA, int begB, int degB, int lane,
    float& o0, float& o1) {
    const int half = lane >> 5, c2 = lane & 31;
    const int beg = half ? begB : begA;
    const int deg = half ? degB : degA;
    const int m = deg < 32 ? deg : 32;
    unsigned ev = 0;
    if (c2 < m) ev = csr_ew[beg + c2];
    int dmax = degA > degB ? degA : degB;
    int jm = dmax < 32 ? dmax : 32;
    jm = (jm + 7) & ~7;
    float a0 = 0.f, a1 = 0.f;
    const int base = half << 5;
    for (int j = 0; j < jm; j += 8) {
        unsigned vv[8]; float ww[8];
#pragma unroll
        for (int k = 0; k < 8; ++k) {
            unsigned p = __shfl(ev, base + j + k);
            ww[k] = wof(p);
            vv[k] = feat32[(size_t)(p & 0xffff) * 32 + c2];
        }
#pragma unroll
        for (int k = 0; k < 8; ++k) {
            a0 = fmaf(ww[k], lo2f(vv[k]), a0);
            a1 = fmaf(ww[k], hi2f(vv[k]), a1);
        }
    }
    int end = beg + deg;
    for (int e = beg + 32; e < end; ++e) {
        unsigned p = csr_ew[e];
        float w = wof(p);
        unsigned v = feat32[(size_t)(p & 0xffff) * 32 + c2];
        a0 = fmaf(w, lo2f(v), a0);
        a1 = fmaf(w, hi2f(v), a1);
    }
    o0 = a0; o1 = a1;
}

// ---------------- layer-0 cand (512 thr, MFMA dense) ----------------
// A-tile sA[64][104] fp16: k0-7 aggX, k8-71 gconv(RH0), k72-95 zero.
__global__ __launch_bounds__(512) void l0_cand(
    const _Float16* __restrict__ RH0h, const float* __restrict__ aggXt, int t,
    const int* __restrict__ rowptr, const unsigned* __restrict__ csr_ew,
    const _Float16* __restrict__ Wc0t, const float* __restrict__ bc,
    const _Float16* __restrict__ Zh, float* __restrict__ h0f,
    unsigned* __restrict__ h01, int N) {
    __shared__ _Float16 sA[64 * 104];
    const int tid = threadIdx.x;
    const int lane = tid & 63;
    const int wid = __builtin_amdgcn_readfirstlane(tid >> 6);
    const int nb = blockIdx.x * 64;
    // zero pad cols 72..103
    { int nl = tid >> 3, k0 = 72 + ((tid & 7) << 2);
#pragma unroll
      for (int q = 0; q < 4; ++q) sA[nl * 104 + k0 + q] = (_Float16)0.f; }
    // aggX fill cols 0..7
    { int nl = tid >> 3, f = tid & 7, n = nb + nl;
      sA[nl * 104 + f] = (n < N) ? (_Float16)aggXt[((size_t)t * N + n) * 8 + f] : (_Float16)0.f; }
    // pair gather cols 8..71
    for (int i = 0; i < 4; ++i) {
        int pr = wid * 4 + i;
        int nlA = pr * 2, nlB = nlA + 1;
        int nA = nb + nlA, nB = nb + nlB;
        int begA = 0, degA = 0, begB = 0, degB = 0;
        if (nA < N) { begA = rowptr[nA]; degA = rowptr[nA + 1] - begA; }
        if (nB < N) { begB = rowptr[nB]; degB = rowptr[nB + 1] - begB; }
        float o0, o1;
        gpair16((const unsigned*)RH0h, csr_ew, begA, degA, begB, degB, lane, o0, o1);
        int nl = (lane < 32) ? nlA : nlB;
        int c2 = lane & 31;
        sA[nl * 104 + 8 + 2 * c2] = (_Float16)o0;
        sA[nl * 104 + 8 + 2 * c2 + 1] = (_Float16)o1;
    }
    __syncthreads();
    // dense: out[64][64] = sA @ Wc0t^T (K=96), tanh
    const int ln15 = lane & 15, quad = lane >> 4;
    const int mt = wid & 3, ng = wid >> 2;       // ng 0..1, 2 N-tiles each
    const int mrow = mt * 16 + ln15;
    f16x8 afr[3];
#pragma unroll
    for (int kc = 0; kc < 3; ++kc)
        afr[kc] = *(const f16x8*)&sA[mrow * 104 + kc * 32 + quad * 8];
    f32x4 acc[2];
    int cols[2];
#pragma unroll
    for (int nt = 0; nt < 2; ++nt) {
        int col = (ng * 2 + nt) * 16 + ln15;
        cols[nt] = col;
        float b = bc[col];
        f32x4 a = {b, b, b, b};
#pragma unroll
        for (int kc = 0; kc < 3; ++kc) {
            f16x8 bfr = *(const f16x8*)&Wc0t[(size_t)col * 96 + kc * 32 + quad * 8];
            a = __builtin_amdgcn_mfma_f32_16x16x32_f16(afr[kc], bfr, a, 0, 0, 0);
        }
        acc[nt] = a;
    }
    __syncthreads();
    // stage c into sA cols 0..63
#pragma unroll
    for (int nt = 0; nt < 2; ++nt) {
#pragma unroll
        for (int r = 0; r < 4; ++r) {
            float e = __expf(2.f * acc[nt][r]);
            float c = 1.f - 2.f / (e + 1.f);
            int row = mt * 16 + quad * 4 + r;
            sA[row * 104 + cols[nt]] = (_Float16)c;
        }
    }
    __syncthreads();
    for (int i = tid; i < 4096; i += 512) {
        int nl = i >> 6, cc = i & 63, n = nb + nl;
        if (n < N) {
            size_t idx = (size_t)n * 64 + cc;
            float z = (float)Zh[idx];
            float hv = h0f[idx];
            float nh = z * hv + (1.f - z) * (float)sA[nl * 104 + cc];
            h0f[idx] = nh;
            reinterpret_cast<__half*>(h01)[idx * 2] = __float2half(nh);
        }
    }
}

// ---------------- layer-1 gate (512 thr, dual gather + MFMA) ----------------
// A-tile sA[64][136]: k0-63 gconv(h0'), k64-127 gconv(h1)
__global__ __launch_bounds__(512) void l1_gate(
    const unsigned* __restrict__ h01, const float* __restrict__ h1f,
    const int* __restrict__ rowptr, const unsigned* __restrict__ csr_ew,
    const _Float16* __restrict__ Wg1t, const float* __restrict__ bg,
    unsigned* __restrict__ Aglobh32, _Float16* __restrict__ Zh,
    _Float16* __restrict__ RH1h, int N) {
    __shared__ _Float16 sA[64 * 136];
    const int tid = threadIdx.x;
    const int lane = tid & 63;
    const int wid = __builtin_amdgcn_readfirstlane(tid >> 6);
    const int nb = blockIdx.x * 64;
    const uint2* __restrict__ f2 = (const uint2*)h01;
    for (int i = 0; i < 4; ++i) {
        int pr = wid * 4 + i;
        int nlA = pr * 2, nlB = nlA + 1;
        int nA = nb + nlA, nB = nb + nlB;
        int begA = 0, degA = 0, begB = 0, degB = 0;
        if (nA < N) { begA = rowptr[nA]; degA = rowptr[nA + 1] - begA; }
        if (nB < N) { begB = rowptr[nB]; degB = rowptr[nB + 1] - begB; }
        const int half = lane >> 5, c2 = lane & 31;
        const int beg = half ? begB : begA;
        const int deg = half ? degB : degA;
        const int m = deg < 32 ? deg : 32;
        unsigned ev = 0;
        if (c2 < m) ev = csr_ew[beg + c2];
        int dmax = degA > degB ? degA : degB;
        int jm = dmax < 32 ? dmax : 32;
        jm = (jm + 7) & ~7;
        float p00 = 0.f, p01 = 0.f, p10 = 0.f, p11 = 0.f;
        const int base = half << 5;
        for (int j = 0; j < jm; j += 8) {
            uint2 vv[8]; float ww[8];
#pragma unroll
            for (int k = 0; k < 8; ++k) {
                unsigned p = __shfl(ev, base + j + k);
                ww[k] = wof(p);
                vv[k] = f2[(size_t)(p & 0xffff) * 32 + c2];
            }
#pragma unroll
            for (int k = 0; k < 8; ++k) {
                p00 = fmaf(ww[k], lo2f(vv[k].x), p00);
                p10 = fmaf(ww[k], hi2f(vv[k].x), p10);
                p01 = fmaf(ww[k], lo2f(vv[k].y), p01);
                p11 = fmaf(ww[k], hi2f(vv[k].y), p11);
            }
        }
        int end = beg + deg;
        for (int e = beg + 32; e < end; ++e) {
            unsigned p = csr_ew[e];
            float w = wof(p);
            uint2 v = f2[(size_t)(p & 0xffff) * 32 + c2];
            p00 = fmaf(w, lo2f(v.x), p00);
            p10 = fmaf(w, hi2f(v.x), p10);
            p01 = fmaf(w, lo2f(v.y), p01);
            p11 = fmaf(w, hi2f(v.y), p11);
        }
        int nl = (lane < 32) ? nlA : nlB;
        int c2w = lane & 31;
        sA[nl * 136 + 2 * c2w] = (_Float16)p00;
        sA[nl * 136 + 2 * c2w + 1] = (_Float16)p01;
        sA[nl * 136 + 64 + 2 * c2w] = (_Float16)p10;
        sA[nl * 136 + 64 + 2 * c2w + 1] = (_Float16)p11;
    }
    __syncthreads();
    // Aglob dump (fp16, packed u32 view) — reads sA cols 0..63
    for (int i = tid; i < 2048; i += 512) {
        int nl = i >> 5, c2 = i & 31, n = nb + nl;
        if (n < N) Aglobh32[(size_t)n * 32 + c2] = ((const unsigned*)sA)[nl * 68 + c2];
    }
    // dense: rz[64][128] = sA @ Wg1t^T (K=128), sigmoid
    const int ln15 = lane & 15, quad = lane >> 4;
    const int mt = wid & 3, ng = wid >> 2;       // ng 0..1, 4 N-tiles each
    const int mrow = mt * 16 + ln15;
    f16x8 afr[4];
#pragma unroll
    for (int kc = 0; kc < 4; ++kc)
        afr[kc] = *(const f16x8*)&sA[mrow * 136 + kc * 32 + quad * 8];
    f32x4 acc[4];
    int cols[4];
#pragma unroll
    for (int nt = 0; nt < 4; ++nt) {
        int col = (ng * 4 + nt) * 16 + ln15;
        cols[nt] = col;
        float b = bg[col];
        f32x4 a = {b, b, b, b};
#pragma unroll
        for (int kc = 0; kc < 4; ++kc) {
            f16x8 bfr = *(const f16x8*)&Wg1t[(size_t)col * 128 + kc * 32 + quad * 8];
            a = __builtin_amdgcn_mfma_f32_16x16x32_f16(afr[kc], bfr, a, 0, 0, 0);
        }
        acc[nt] = a;
    }
    __syncthreads();
    // stage r (cols 0-63) and z (cols 64-127) into sA
#pragma unroll
    for (int nt = 0; nt < 4; ++nt) {
#pragma unroll
        for (int r = 0; r < 4; ++r) {
            float s = 1.f / (1.f + __expf(-acc[nt][r]));
            int row = mt * 16 + quad * 4 + r;
            sA[row * 136 + cols[nt]] = (_Float16)s;
        }
    }
    __syncthreads();
    for (int i = tid; i < 4096; i += 512) {
        int nl = i >> 6, cc = i & 63, n = nb + nl;
        if (n < N) {
            size_t idx = (size_t)n * 64 + cc;
            float r = (float)sA[nl * 136 + cc];
            float z = (float)sA[nl * 136 + 64 + cc];
            RH1h[idx] = (_Float16)(r * h1f[idx]);
            Zh[idx] = (_Float16)z;
        }
    }
}

// ---------------- layer-1 cand + fused gate0(t+1) (512 thr, MFMA) ----------
// sA[64][136]: k0-63 = Aglobh (gconv h0'), k64-127 = gconv(RH1).
// sX[64][40]: k0-7 aggX(t+1), rest 0.
__global__ __launch_bounds__(512) void l1_cand_fused(
    const _Float16* __restrict__ RH1h, const unsigned* __restrict__ Aglobh32,
    const float* __restrict__ aggXt, int tn, int do_gate, int final,
    const int* __restrict__ rowptr, const unsigned* __restrict__ csr_ew,
    const _Float16* __restrict__ Wc1t, const float* __restrict__ bc1,
    const _Float16* __restrict__ Wg0t_h, const _Float16* __restrict__ Wg0t_x,
    const float* __restrict__ bg0, const float* __restrict__ h0f,
    _Float16* __restrict__ Zh, _Float16* __restrict__ RH0h,
    float* __restrict__ h1f, unsigned* __restrict__ h01,
    const float* __restrict__ Wout, const float* __restrict__ bout,
    float* __restrict__ out, int N) {
    __shared__ _Float16 sA[64 * 136];
    __shared__ _Float16 sX[64 * 40];
    const int tid = threadIdx.x;
    const int lane = tid & 63;
    const int wid = __builtin_amdgcn_readfirstlane(tid >> 6);
    const int nb = blockIdx.x * 64;
    // sX zero (cols 8..39) + aggX fill (cols 0..7)
    { int nl = tid >> 3, k0 = 8 + ((tid & 7) << 2);
#pragma unroll
      for (int q = 0; q < 4; ++q) sX[nl * 40 + k0 + q] = (_Float16)0.f; }
    if (do_gate) {
        int nl = tid >> 3, f = tid & 7, n = nb + nl;
        sX[nl * 40 + f] = (n < N) ? (_Float16)aggXt[((size_t)tn * N + n) * 8 + f] : (_Float16)0.f;
    }
    // Aglobh -> sA cols 0..63 (u32 packed)
    for (int i = tid; i < 2048; i += 512) {
        int nl = i >> 5, c2 = i & 31, n = nb + nl;
        ((unsigned*)sA)[nl * 68 + c2] = (n < N) ? Aglobh32[(size_t)n * 32 + c2] : 0u;
    }
    // pair gather gconv(RH1) -> sA cols 64..127
    for (int i = 0; i < 4; ++i) {
        int pr = wid * 4 + i;
        int nlA = pr * 2, nlB = nlA + 1;
        int nA = nb + nlA, nB = nb + nlB;
        int begA = 0, degA = 0, begB = 0, degB = 0;
        if (nA < N) { begA = rowptr[nA]; degA = rowptr[nA + 1] - begA; }
        if (nB < N) { begB = rowptr[nB]; degB = rowptr[nB + 1] - begB; }
        float o0, o1;
        gpair16((const unsigned*)RH1h, csr_ew, begA, degA, begB, degB, lane, o0, o1);
        int nl = (lane < 32) ? nlA : nlB;
        int c2 = lane & 31;
        sA[nl * 136 + 64 + 2 * c2] = (_Float16)o0;
        sA[nl * 136 + 64 + 2 * c2 + 1] = (_Float16)o1;
    }
    __syncthreads();
    const int ln15 = lane & 15, quad = lane >> 4;
    const int mt = wid & 3, ng = wid >> 2;
    const int mrow = mt * 16 + ln15;
    f16x8 afr[4];
#pragma unroll
    for (int kc = 0; kc < 4; ++kc)
        afr[kc] = *(const f16x8*)&sA[mrow * 136 + kc * 32 + quad * 8];
    // cand: c1[64][64] = sA @ Wc1t^T (K=128), 2 N-tiles/wave
    f32x4 accc[2];
    int colc[2];
#pragma unroll
    for (int nt = 0; nt < 2; ++nt) {
        int col = (ng * 2 + nt) * 16 + ln15;
        colc[nt] = col;
        float b = bc1[col];
        f32x4 a = {b, b, b, b};
#pragma unroll
        for (int kc = 0; kc < 4; ++kc) {
            f16x8 bfr = *(const f16x8*)&Wc1t[(size_t)col * 128 + kc * 32 + quad * 8];
            a = __builtin_amdgcn_mfma_f32_16x16x32_f16(afr[kc], bfr, a, 0, 0, 0);
        }
        accc[nt] = a;
    }
    // gate0(t+1): rz0[64][128] = sX@Wg0t_x + sA(0:64)@Wg0t_h, 4 N-tiles/wave
    f32x4 accg[4];
    int colg[4];
    if (do_gate) {
        f16x8 xfr = *(const f16x8*)&sX[mrow * 40 + quad * 8];
#pragma unroll
        for (int nt = 0; nt < 4; ++nt) {
            int col = (ng * 4 + nt) * 16 + ln15;
            colg[nt] = col;
            float b = bg0[col];
            f32x4 a = {b, b, b, b};
            f16x8 bx = *(const f16x8*)&Wg0t_x[(size_t)col * 32 + quad * 8];
            a = __builtin_amdgcn_mfma_f32_16x16x32_f16(xfr, bx, a, 0, 0, 0);
#pragma unroll
            for (int kc = 0; kc < 2; ++kc) {
                f16x8 bfr = *(const f16x8*)&Wg0t_h[(size_t)col * 64 + kc * 32 + quad * 8];
                a = __builtin_amdgcn_mfma_f32_16x16x32_f16(afr[kc], bfr, a, 0, 0, 0);
            }
            accg[nt] = a;
        }
    }
    __syncthreads();
    // stage: c1 -> sA cols 64..127; r0 -> sA cols 0..63 (z0 stays in regs)
#pragma unroll
    for (int nt = 0; nt < 2; ++nt) {
#pragma unroll
        for (int r = 0; r < 4; ++r) {
            float e = __expf(2.f * accc[nt][r]);
            float c = 1.f - 2.f / (e + 1.f);
            int row = mt * 16 + quad * 4 + r;
            sA[row * 136 + 64 + colc[nt]] = (_Float16)c;
        }
    }
    if (do_gate) {
#pragma unroll
        for (int nt = 0; nt < 4; ++nt) {
            if (colg[nt] < 64) {
#pragma unroll
                for (int r = 0; r < 4; ++r) {
                    float s = 1.f / (1.f + __expf(-accg[nt][r]));
                    int row = mt * 16 + quad * 4 + r;
                    sA[row * 136 + colg[nt]] = (_Float16)s;
                }
            }
        }
    }
    __syncthreads();
    // epilogue-1: h1 update (+RH0h, +final out)
    for (int i = tid; i < 4096; i += 512) {
        int nl = i >> 6, cc = i & 63, n = nb + nl;
        float nh = 0.f;
        if (n < N) {
            size_t idx = (size_t)n * 64 + cc;
            float z1 = (float)Zh[idx];
            float hv = h1f[idx];
            nh = z1 * hv + (1.f - z1) * (float)sA[nl * 136 + 64 + cc];
            if (!final) {
                h1f[idx] = nh;
                reinterpret_cast<__half*>(h01)[idx * 2 + 1] = __float2half(nh);
            }
            if (do_gate) RH0h[idx] = (_Float16)((float)sA[nl * 136 + cc] * h0f[idx]);
        }
        if (final) {
            float p = nh * Wout[cc];
            for (int off = 32; off > 0; off >>= 1) p += __shfl_down(p, off);
            if (cc == 0 && n < N) out[n] = p + bout[0];
        }
    }
    if (do_gate) {
        __syncthreads();
        // stage z0 (gate cols >= 64) -> sA cols 0..63
#pragma unroll
        for (int nt = 0; nt < 4; ++nt) {
            if (colg[nt] >= 64) {
#pragma unroll
                for (int r = 0; r < 4; ++r) {
                    float s = 1.f / (1.f + __expf(-accg[nt][r]));
                    int row = mt * 16 + quad * 4 + r;
                    sA[row * 136 + (colg[nt] - 64)] = (_Float16)s;
                }
            }
        }
        __syncthreads();
        for (int i = tid; i < 4096; i += 512) {
            int nl = i >> 6, cc = i & 63, n = nb + nl;
            if (n < N) Zh[(size_t)n * 64 + cc] = sA[nl * 136 + cc];
        }
    }
}

static inline size_t align16(size_t v) { return (v + 15) & ~(size_t)15; }

extern "C" void kernel_launch(void* const* d_in, const int* in_sizes, int n_in,
                              void* d_out, int out_size, void* d_ws, size_t ws_size,
                              hipStream_t stream) {
    const float* x   = (const float*)d_in[0];
    const int*   ei  = (const int*)d_in[1];
    const float* ew  = (const float*)d_in[2];
    const float* Wg0 = (const float*)d_in[3];
    const float* bg0 = (const float*)d_in[4];
    const float* Wc0 = (const float*)d_in[5];
    const float* bc0 = (const float*)d_in[6];
    const float* Wg1 = (const float*)d_in[7];
    const float* bg1 = (const float*)d_in[8];
    const float* Wc1 = (const float*)d_in[9];
    const float* bc1 = (const float*)d_in[10];
    const float* Wout = (const float*)d_in[11];
    const float* bout = (const float*)d_in[12];

    const int N = in_sizes[0] / FT;
    const int E = in_sizes[2];
    const int* src = ei;
    const int* dst = ei + E;

    char* base = (char*)d_ws;
    size_t off = 0;
    int* deg = (int*)(base + off);            off = align16(off + (size_t)N * 4);
    int* cursor = (int*)(base + off);         off = align16(off + (size_t)N * 4);
    int* rowptr = (int*)(base + off);         off = align16(off + (size_t)(N + 1) * 4);
    int* part = (int*)(base + off);           off = align16(off + 256 * 4);
    unsigned* csr_ew = (unsigned*)(base + off);  off = align16(off + (size_t)E * 4);
    float* aggXt = (float*)(base + off);      off = align16(off + (size_t)N * FT * 4);
    float* h0f = (float*)(base + off);        off = align16(off + (size_t)N * 64 * 4);
    float* h1f = (float*)(base + off);        off = align16(off + (size_t)N * 64 * 4);
    unsigned* h01 = (unsigned*)(base + off);  off = align16(off + (size_t)N * 64 * 4);
    unsigned* Aglobh32 = (unsigned*)(base + off); off = align16(off + (size_t)N * 32 * 4);
    _Float16* Zh = (_Float16*)(base + off);   off = align16(off + (size_t)N * 64 * 2);
    _Float16* RH0h = (_Float16*)(base + off); off = align16(off + (size_t)N * 64 * 2);
    _Float16* RH1h = (_Float16*)(base + off); off = align16(off + (size_t)N * 64 * 2);
    _Float16* xh = (_Float16*)(base + off);   off = align16(off + (size_t)N * FT * 2);
    _Float16* Wg1t = (_Float16*)(base + off); off = align16(off + 128 * 128 * 2);
    _Float16* Wc1t = (_Float16*)(base + off); off = align16(off + 64 * 128 * 2);
    _Float16* Wc0t = (_Float16*)(base + off); off = align16(off + 64 * 96 * 2);
    _Float16* Wg0t_h = (_Float16*)(base + off); off = align16(off + 128 * 64 * 2);
    _Float16* Wg0t_x = (_Float16*)(base + off); off = align16(off + 128 * 32 * 2);

    const int gE   = (E + 255) / 256;
    const int gN4  = (N + 3) / 4;
    const int gN64 = (N + 63) / 64;
    const int G    = (N + 255) / 256;

    hipMemsetAsync(deg, 0, (size_t)N * 4, stream);
    hipMemsetAsync(h0f, 0, (size_t)N * 64 * 4, stream);
    hipMemsetAsync(h1f, 0, (size_t)N * 64 * 4, stream);
    hipMemsetAsync(h01, 0, (size_t)N * 64 * 4, stream);
    hipMemsetAsync(RH0h, 0, (size_t)N * 64 * 2, stream);

    x2h_k<<<(N * FT + 255) / 256, 256, 0, stream>>>(x, xh, N * FT);
    wprep_k<<<64, 256, 0, stream>>>(Wg0, Wc0, Wg1, Wc1, Wg1t, Wc1t, Wc0t, Wg0t_h, Wg0t_x);
    hist_k<<<gE, 256, 0, stream>>>(dst, deg, E);
    partial_k<<<G, 256, 0, stream>>>(deg, part, N);
    scanpart_k<<<1, 256, 0, stream>>>(part, rowptr, G, N);
    scanchunk_k<<<G, 256, 0, stream>>>(deg, part, rowptr, cursor, N);
    fill_k<<<gE, 256, 0, stream>>>(src, dst, ew, cursor, csr_ew, E);
    gather96_k<<<gN4, 256, 0, stream>>>(xh, rowptr, csr_ew, aggXt, N);

    // t=0: h0=0 -> RH0h=0 (memset); z0 from aggX only
    g0z_k<<<(N * 64 + 255) / 256, 256, 0, stream>>>(aggXt, Wg0, bg0, Zh, N);

    for (int t = 0; t < TSTEPS; ++t) {
        l0_cand<<<gN64, 512, 0, stream>>>(RH0h, aggXt, t, rowptr, csr_ew,
                                          Wc0t, bc0, Zh, h0f, h01, N);
        l1_gate<<<gN64, 512, 0, stream>>>(h01, h1f, rowptr, csr_ew,
                                          Wg1t, bg1, Aglobh32, Zh, RH1h, N);
        l1_cand_fused<<<gN64, 512, 0, stream>>>(RH1h, Aglobh32, aggXt, t + 1,
                                                (t + 1 < TSTEPS) ? 1 : 0,
                                                (t + 1 == TSTEPS) ? 1 : 0,
                                                rowptr, csr_ew,
                                                Wc1t, bc1, Wg0t_h, Wg0t_x, bg0,
                                                h0f, Zh, RH0h, h1f, h01,
                                                Wout, bout, (float*)d_out, N);
    }
}

// Round 12
// 1938.059 us; speedup vs baseline: 1.3981x; 1.0068x over previous
//
#include <hip/hip_runtime.h>
#include <hip/hip_fp16.h>

// TGCN 2-layer, T=12, F=8, H=64, N=50k, E=800k.
// R12 = R11 with 1024-thread cell kernels: 16 waves/block, 2 gather-pairs per
// wave (serial dependent-batch chain halved: 12 -> 6 round trips), 2 blocks/CU
// resident -> 32 waves/CU (hw max). Pair mapping + summation order unchanged
// -> bitwise identical to R11 (absmax 0.01953125).

#define FT 96
#define TSTEPS 12

typedef _Float16 f16x8 __attribute__((ext_vector_type(8)));
typedef float f32x4 __attribute__((ext_vector_type(4)));

static __device__ __forceinline__ float lo2f(unsigned v) {
    __half2 h2 = *reinterpret_cast<const __half2*>(&v);
    return __low2float(h2);
}
static __device__ __forceinline__ float hi2f(unsigned v) {
    __half2 h2 = *reinterpret_cast<const __half2*>(&v);
    return __high2float(h2);
}
static __device__ __forceinline__ float wof(unsigned p) {
    return __half2float(__ushort_as_half((unsigned short)(p >> 16)));
}

// ---------------- CSR build ----------------
__global__ void hist_k(const int* __restrict__ dst, int* __restrict__ deg, int E) {
    int e = blockIdx.x * blockDim.x + threadIdx.x;
    if (e < E) atomicAdd(&deg[dst[e]], 1);
}

__global__ __launch_bounds__(256) void partial_k(const int* __restrict__ deg,
                                                 int* __restrict__ part, int N) {
    __shared__ int sm[256];
    int i = blockIdx.x * 256 + threadIdx.x;
    sm[threadIdx.x] = (i < N) ? deg[i] : 0;
    __syncthreads();
    for (int off = 128; off > 0; off >>= 1) {
        if (threadIdx.x < off) sm[threadIdx.x] += sm[threadIdx.x + off];
        __syncthreads();
    }
    if (threadIdx.x == 0) part[blockIdx.x] = sm[0];
}

__global__ __launch_bounds__(256) void scanpart_k(int* __restrict__ part,
                                                  int* __restrict__ rowptr,
                                                  int G, int N) {
    __shared__ int sm[256];
    int v = (threadIdx.x < G) ? part[threadIdx.x] : 0;
    sm[threadIdx.x] = v;
    __syncthreads();
    for (int off = 1; off < 256; off <<= 1) {
        int t = (threadIdx.x >= (unsigned)off) ? sm[threadIdx.x - off] : 0;
        __syncthreads();
        sm[threadIdx.x] += t;
        __syncthreads();
    }
    if (threadIdx.x < G) part[threadIdx.x] = sm[threadIdx.x] - v;
    if (threadIdx.x == 255) rowptr[N] = sm[255];
}

__global__ __launch_bounds__(256) void scanchunk_k(const int* __restrict__ deg,
                                                   const int* __restrict__ part,
                                                   int* __restrict__ rowptr,
                                                   int* __restrict__ cursor, int N) {
    __shared__ int sm[256];
    int i = blockIdx.x * 256 + threadIdx.x;
    int v = (i < N) ? deg[i] : 0;
    sm[threadIdx.x] = v;
    __syncthreads();
    for (int off = 1; off < 256; off <<= 1) {
        int t = (threadIdx.x >= (unsigned)off) ? sm[threadIdx.x - off] : 0;
        __syncthreads();
        sm[threadIdx.x] += t;
        __syncthreads();
    }
    int excl = sm[threadIdx.x] - v + part[blockIdx.x];
    if (i < N) { rowptr[i] = excl; cursor[i] = excl; }
}

__global__ void fill_k(const int* __restrict__ src, const int* __restrict__ dst,
                       const float* __restrict__ ew, int* __restrict__ cursor,
                       unsigned* __restrict__ csr_ew, int E) {
    int e = blockIdx.x * blockDim.x + threadIdx.x;
    if (e >= E) return;
    int pos = atomicAdd(&cursor[dst[e]], 1);
    unsigned hw = (unsigned)__half_as_ushort(__float2half(ew[e]));
    csr_ew[pos] = (unsigned)src[e] | (hw << 16);
}

__global__ void x2h_k(const float* __restrict__ x, _Float16* __restrict__ xh, int M) {
    int i = blockIdx.x * blockDim.x + threadIdx.x;
    if (i < M) xh[i] = (_Float16)x[i];
}

// weight prep: fp16 transposed [C][K] layouts
__global__ void wprep_k(const float* __restrict__ Wg0, const float* __restrict__ Wc0,
                        const float* __restrict__ Wg1, const float* __restrict__ Wc1,
                        _Float16* __restrict__ Wg1t, _Float16* __restrict__ Wc1t,
                        _Float16* __restrict__ Wc0t, _Float16* __restrict__ Wg0t_h,
                        _Float16* __restrict__ Wg0t_x) {
    int i = blockIdx.x * 256 + threadIdx.x;
    if (i < 128 * 128) { int c = i >> 7, k = i & 127; Wg1t[i] = (_Float16)Wg1[k * 128 + c]; }
    if (i < 64 * 128)  { int c = i >> 7, k = i & 127; Wc1t[i] = (_Float16)Wc1[k * 64 + c]; }
    if (i < 64 * 96)   { int c = i / 96, k = i - c * 96;
                         Wc0t[i] = (k < 72) ? (_Float16)Wc0[k * 64 + c] : (_Float16)0.f; }
    if (i < 128 * 64)  { int c = i >> 6, k = i & 63; Wg0t_h[i] = (_Float16)Wg0[(8 + k) * 128 + c]; }
    if (i < 128 * 32)  { int c = i >> 5, k = i & 31;
                         Wg0t_x[i] = (k < 8) ? (_Float16)Wg0[k * 128 + c] : (_Float16)0.f; }
}

// gather of xh (96 fp16 ch/node), writes transposed aggXt[t][n][f]
__global__ __launch_bounds__(256) void gather96_k(
    const _Float16* __restrict__ xh, const int* __restrict__ rowptr,
    const unsigned* __restrict__ csr_ew, float* __restrict__ aggXt, int N) {
    int n = blockIdx.x * 4 + (threadIdx.x >> 6);
    if (n >= N) return;
    int c = threadIdx.x & 63;
    int beg = rowptr[n], end = rowptr[n + 1];
    int deg = end - beg;
    float a0 = 0.f, a1 = 0.f;
    unsigned ev = 0;
    if (c < deg) ev = csr_ew[beg + c];
    int m = deg < 64 ? deg : 64;
    int m8 = (m + 7) & ~7;
#pragma unroll 8
    for (int j = 0; j < m8; ++j) {
        unsigned p = __shfl(ev, j);
        int s = p & 0xffff;
        float w = wof(p);
        const _Float16* row = xh + (size_t)s * FT;
        a0 = fmaf(w, (float)row[c], a0);
        if (c < 32) a1 = fmaf(w, (float)row[64 + c], a1);
    }
    for (int e = beg + 64; e < end; ++e) {
        unsigned p = csr_ew[e];
        int s = p & 0xffff;
        float w = wof(p);
        const _Float16* row = xh + (size_t)s * FT;
        a0 = fmaf(w, (float)row[c], a0);
        if (c < 32) a1 = fmaf(w, (float)row[64 + c], a1);
    }
    { int f = c / 12, tt = c - f * 12;
      aggXt[((size_t)tt * N + n) * 8 + f] = a0; }
    if (c < 32) { int cc = 64 + c; int f = cc / 12, tt = cc - f * 12;
      aggXt[((size_t)tt * N + n) * 8 + f] = a1; }
}

// t=0 gate0 (h0=0): only z0 needed (r0*h0 = 0)
__global__ void g0z_k(const float* __restrict__ aggXt, const float* __restrict__ Wg0,
                      const float* __restrict__ bg0, _Float16* __restrict__ Zh, int N) {
    int i = blockIdx.x * blockDim.x + threadIdx.x;
    int n = i >> 6;
    if (n >= N) return;
    int c = i & 63;
    float acc = bg0[64 + c];
#pragma unroll
    for (int f = 0; f < 8; ++f) acc += aggXt[(size_t)n * 8 + f] * Wg0[f * 128 + 64 + c];
    Zh[(size_t)n * 64 + c] = (_Float16)(1.f / (1.f + __expf(-acc)));
}

// pair-wave gather: lanes 0-31 node A, 32-63 node B; lane = channels 2c2,2c2+1
__device__ __forceinline__ void gpair16(const unsigned* __restrict__ feat32,
    const unsigned* __restrict__ csr_ew,
    int begA, int degA, int begB, int degB, int lane,
    float& o0, float& o1) {
    const int half = lane >> 5, c2 = lane & 31;
    const int beg = half ? begB : begA;
    const int deg = half ? degB : degA;
    const int m = deg < 32 ? deg : 32;
    unsigned ev = 0;
    if (c2 < m) ev = csr_ew[beg + c2];
    int dmax = degA > degB ? degA : degB;
    int jm = dmax < 32 ? dmax : 32;
    jm = (jm + 7) & ~7;
    float a0 = 0.f, a1 = 0.f;
    const int base = half << 5;
    for (int j = 0; j < jm; j += 8) {
        unsigned vv[8]; float ww[8];
#pragma unroll
        for (int k = 0; k < 8; ++k) {
            unsigned p = __shfl(ev, base + j + k);
            ww[k] = wof(p);
            vv[k] = feat32[(size_t)(p & 0xffff) * 32 + c2];
        }
#pragma unroll
        for (int k = 0; k < 8; ++k) {
            a0 = fmaf(ww[k], lo2f(vv[k]), a0);
            a1 = fmaf(ww[k], hi2f(vv[k]), a1);
        }
    }
    int end = beg + deg;
    for (int e = beg + 32; e < end; ++e) {
        unsigned p = csr_ew[e];
        float w = wof(p);
        unsigned v = feat32[(size_t)(p & 0xffff) * 32 + c2];
        a0 = fmaf(w, lo2f(v), a0);
        a1 = fmaf(w, hi2f(v), a1);
    }
    o0 = a0; o1 = a1;
}

// ---------------- layer-0 cand (1024 thr, MFMA dense) ----------------
// A-tile sA[64][104] fp16: k0-7 aggX, k8-71 gconv(RH0), k72-95 zero.
__global__ __launch_bounds__(1024) void l0_cand(
    const _Float16* __restrict__ RH0h, const float* __restrict__ aggXt, int t,
    const int* __restrict__ rowptr, const unsigned* __restrict__ csr_ew,
    const _Float16* __restrict__ Wc0t, const float* __restrict__ bc,
    const _Float16* __restrict__ Zh, float* __restrict__ h0f,
    unsigned* __restrict__ h01, int N) {
    __shared__ _Float16 sA[64 * 104];
    const int tid = threadIdx.x;
    const int lane = tid & 63;
    const int wid = __builtin_amdgcn_readfirstlane(tid >> 6);   // 0..15
    const int nb = blockIdx.x * 64;
    // zero pad cols 72..103 + aggX fill cols 0..7 (first 512 threads)
    if (tid < 512) {
        int nl = tid >> 3, k0 = 72 + ((tid & 7) << 2);
#pragma unroll
        for (int q = 0; q < 4; ++q) sA[nl * 104 + k0 + q] = (_Float16)0.f;
        int f = tid & 7, n = nb + nl;
        sA[nl * 104 + f] = (n < N) ? (_Float16)aggXt[((size_t)t * N + n) * 8 + f] : (_Float16)0.f;
    }
    // pair gather cols 8..71: 2 pairs per wave
    for (int i = 0; i < 2; ++i) {
        int pr = wid * 2 + i;
        int nlA = pr * 2, nlB = nlA + 1;
        int nA = nb + nlA, nB = nb + nlB;
        int begA = 0, degA = 0, begB = 0, degB = 0;
        if (nA < N) { begA = rowptr[nA]; degA = rowptr[nA + 1] - begA; }
        if (nB < N) { begB = rowptr[nB]; degB = rowptr[nB + 1] - begB; }
        float o0, o1;
        gpair16((const unsigned*)RH0h, csr_ew, begA, degA, begB, degB, lane, o0, o1);
        int nl = (lane < 32) ? nlA : nlB;
        int c2 = lane & 31;
        sA[nl * 104 + 8 + 2 * c2] = (_Float16)o0;
        sA[nl * 104 + 8 + 2 * c2 + 1] = (_Float16)o1;
    }
    __syncthreads();
    // dense: out[64][64] = sA @ Wc0t^T (K=96), tanh; 1 tile per wave (4x4 tiles)
    const int ln15 = lane & 15, quad = lane >> 4;
    const int mt = wid & 3, nc = wid >> 2;      // mt 0..3, nc 0..3
    const int mrow = mt * 16 + ln15;
    const int col = nc * 16 + ln15;
    f16x8 afr[3];
#pragma unroll
    for (int kc = 0; kc < 3; ++kc)
        afr[kc] = *(const f16x8*)&sA[mrow * 104 + kc * 32 + quad * 8];
    float b = bc[col];
    f32x4 acc = {b, b, b, b};
#pragma unroll
    for (int kc = 0; kc < 3; ++kc) {
        f16x8 bfr = *(const f16x8*)&Wc0t[(size_t)col * 96 + kc * 32 + quad * 8];
        acc = __builtin_amdgcn_mfma_f32_16x16x32_f16(afr[kc], bfr, acc, 0, 0, 0);
    }
    __syncthreads();
    // stage c into sA cols 0..63
#pragma unroll
    for (int r = 0; r < 4; ++r) {
        float e = __expf(2.f * acc[r]);
        float c = 1.f - 2.f / (e + 1.f);
        int row = mt * 16 + quad * 4 + r;
        sA[row * 104 + col] = (_Float16)c;
    }
    __syncthreads();
    for (int i = tid; i < 4096; i += 1024) {
        int nl = i >> 6, cc = i & 63, n = nb + nl;
        if (n < N) {
            size_t idx = (size_t)n * 64 + cc;
            float z = (float)Zh[idx];
            float hv = h0f[idx];
            float nh = z * hv + (1.f - z) * (float)sA[nl * 104 + cc];
            h0f[idx] = nh;
            reinterpret_cast<__half*>(h01)[idx * 2] = __float2half(nh);
        }
    }
}

// ---------------- layer-1 gate (1024 thr, dual gather + MFMA) ---------------
// A-tile sA[64][136]: k0-63 gconv(h0'), k64-127 gconv(h1)
__global__ __launch_bounds__(1024) void l1_gate(
    const unsigned* __restrict__ h01, const float* __restrict__ h1f,
    const int* __restrict__ rowptr, const unsigned* __restrict__ csr_ew,
    const _Float16* __restrict__ Wg1t, const float* __restrict__ bg,
    unsigned* __restrict__ Aglobh32, _Float16* __restrict__ Zh,
    _Float16* __restrict__ RH1h, int N) {
    __shared__ _Float16 sA[64 * 136];
    const int tid = threadIdx.x;
    const int lane = tid & 63;
    const int wid = __builtin_amdgcn_readfirstlane(tid >> 6);   // 0..15
    const int nb = blockIdx.x * 64;
    const uint2* __restrict__ f2 = (const uint2*)h01;
    for (int i = 0; i < 2; ++i) {
        int pr = wid * 2 + i;
        int nlA = pr * 2, nlB = nlA + 1;
        int nA = nb + nlA, nB = nb + nlB;
        int begA = 0, degA = 0, begB = 0, degB = 0;
        if (nA < N) { begA = rowptr[nA]; degA = rowptr[nA + 1] - begA; }
        if (nB < N) { begB = rowptr[nB]; degB = rowptr[nB + 1] - begB; }
        const int half = lane >> 5, c2 = lane & 31;
        const int beg = half ? begB : begA;
        const int deg = half ? degB : degA;
        const int m = deg < 32 ? deg : 32;
        unsigned ev = 0;
        if (c2 < m) ev = csr_ew[beg + c2];
        int dmax = degA > degB ? degA : degB;
        int jm = dmax < 32 ? dmax : 32;
        jm = (jm + 7) & ~7;
        float p00 = 0.f, p01 = 0.f, p10 = 0.f, p11 = 0.f;
        const int base = half << 5;
        for (int j = 0; j < jm; j += 8) {
            uint2 vv[8]; float ww[8];
#pragma unroll
            for (int k = 0; k < 8; ++k) {
                unsigned p = __shfl(ev, base + j + k);
                ww[k] = wof(p);
                vv[k] = f2[(size_t)(p & 0xffff) * 32 + c2];
            }
#pragma unroll
            for (int k = 0; k < 8; ++k) {
                p00 = fmaf(ww[k], lo2f(vv[k].x), p00);
                p10 = fmaf(ww[k], hi2f(vv[k].x), p10);
                p01 = fmaf(ww[k], lo2f(vv[k].y), p01);
                p11 = fmaf(ww[k], hi2f(vv[k].y), p11);
            }
        }
        int end = beg + deg;
        for (int e = beg + 32; e < end; ++e) {
            unsigned p = csr_ew[e];
            float w = wof(p);
            uint2 v = f2[(size_t)(p & 0xffff) * 32 + c2];
            p00 = fmaf(w, lo2f(v.x), p00);
            p10 = fmaf(w, hi2f(v.x), p10);
            p01 = fmaf(w, lo2f(v.y), p01);
            p11 = fmaf(w, hi2f(v.y), p11);
        }
        int nl = (lane < 32) ? nlA : nlB;
        int c2w = lane & 31;
        sA[nl * 136 + 2 * c2w] = (_Float16)p00;
        sA[nl * 136 + 2 * c2w + 1] = (_Float16)p01;
        sA[nl * 136 + 64 + 2 * c2w] = (_Float16)p10;
        sA[nl * 136 + 64 + 2 * c2w + 1] = (_Float16)p11;
    }
    __syncthreads();
    // Aglob dump (fp16, packed u32 view) — reads sA cols 0..63
    for (int i = tid; i < 2048; i += 1024) {
        int nl = i >> 5, c2 = i & 31, n = nb + nl;
        if (n < N) Aglobh32[(size_t)n * 32 + c2] = ((const unsigned*)sA)[nl * 68 + c2];
    }
    // dense: rz[64][128] = sA @ Wg1t^T (K=128), sigmoid; 2 tiles per wave
    const int ln15 = lane & 15, quad = lane >> 4;
    const int mt = wid & 3, ng = wid >> 2;       // ng 0..3, 2 N-tiles each
    const int mrow = mt * 16 + ln15;
    f16x8 afr[4];
#pragma unroll
    for (int kc = 0; kc < 4; ++kc)
        afr[kc] = *(const f16x8*)&sA[mrow * 136 + kc * 32 + quad * 8];
    f32x4 acc[2];
    int cols[2];
#pragma unroll
    for (int nt = 0; nt < 2; ++nt) {
        int col = (ng * 2 + nt) * 16 + ln15;
        cols[nt] = col;
        float b = bg[col];
        f32x4 a = {b, b, b, b};
#pragma unroll
        for (int kc = 0; kc < 4; ++kc) {
            f16x8 bfr = *(const f16x8*)&Wg1t[(size_t)col * 128 + kc * 32 + quad * 8];
            a = __builtin_amdgcn_mfma_f32_16x16x32_f16(afr[kc], bfr, a, 0, 0, 0);
        }
        acc[nt] = a;
    }
    __syncthreads();
    // stage r (cols 0-63) and z (cols 64-127) into sA
#pragma unroll
    for (int nt = 0; nt < 2; ++nt) {
#pragma unroll
        for (int r = 0; r < 4; ++r) {
            float s = 1.f / (1.f + __expf(-acc[nt][r]));
            int row = mt * 16 + quad * 4 + r;
            sA[row * 136 + cols[nt]] = (_Float16)s;
        }
    }
    __syncthreads();
    for (int i = tid; i < 4096; i += 1024) {
        int nl = i >> 6, cc = i & 63, n = nb + nl;
        if (n < N) {
            size_t idx = (size_t)n * 64 + cc;
            float r = (float)sA[nl * 136 + cc];
            float z = (float)sA[nl * 136 + 64 + cc];
            RH1h[idx] = (_Float16)(r * h1f[idx]);
            Zh[idx] = (_Float16)z;
        }
    }
}

// ---------------- layer-1 cand + fused gate0(t+1) (1024 thr, MFMA) ---------
// sA[64][136]: k0-63 = Aglobh (gconv h0'), k64-127 = gconv(RH1).
// sX[64][40]: k0-7 aggX(t+1), rest 0.
__global__ __launch_bounds__(1024) void l1_cand_fused(
    const _Float16* __restrict__ RH1h, const unsigned* __restrict__ Aglobh32,
    const float* __restrict__ aggXt, int tn, int do_gate, int final,
    const int* __restrict__ rowptr, const unsigned* __restrict__ csr_ew,
    const _Float16* __restrict__ Wc1t, const float* __restrict__ bc1,
    const _Float16* __restrict__ Wg0t_h, const _Float16* __restrict__ Wg0t_x,
    const float* __restrict__ bg0, const float* __restrict__ h0f,
    _Float16* __restrict__ Zh, _Float16* __restrict__ RH0h,
    float* __restrict__ h1f, unsigned* __restrict__ h01,
    const float* __restrict__ Wout, const float* __restrict__ bout,
    float* __restrict__ out, int N) {
    __shared__ _Float16 sA[64 * 136];
    __shared__ _Float16 sX[64 * 40];
    const int tid = threadIdx.x;
    const int lane = tid & 63;
    const int wid = __builtin_amdgcn_readfirstlane(tid >> 6);   // 0..15
    const int nb = blockIdx.x * 64;
    // sX zero (cols 8..39) + aggX fill (cols 0..7) — first 512 threads
    if (tid < 512) {
        int nl = tid >> 3, k0 = 8 + ((tid & 7) << 2);
#pragma unroll
        for (int q = 0; q < 4; ++q) sX[nl * 40 + k0 + q] = (_Float16)0.f;
        if (do_gate) {
            int f = tid & 7, n = nb + nl;
            sX[nl * 40 + f] = (n < N) ? (_Float16)aggXt[((size_t)tn * N + n) * 8 + f] : (_Float16)0.f;
        }
    }
    // Aglobh -> sA cols 0..63 (u32 packed)
    for (int i = tid; i < 2048; i += 1024) {
        int nl = i >> 5, c2 = i & 31, n = nb + nl;
        ((unsigned*)sA)[nl * 68 + c2] = (n < N) ? Aglobh32[(size_t)n * 32 + c2] : 0u;
    }
    // pair gather gconv(RH1) -> sA cols 64..127: 2 pairs per wave
    for (int i = 0; i < 2; ++i) {
        int pr = wid * 2 + i;
        int nlA = pr * 2, nlB = nlA + 1;
        int nA = nb + nlA, nB = nb + nlB;
        int begA = 0, degA = 0, begB = 0, degB = 0;
        if (nA < N) { begA = rowptr[nA]; degA = rowptr[nA + 1] - begA; }
        if (nB < N) { begB = rowptr[nB]; degB = rowptr[nB + 1] - begB; }
        float o0, o1;
        gpair16((const unsigned*)RH1h, csr_ew, begA, degA, begB, degB, lane, o0, o1);
        int nl = (lane < 32) ? nlA : nlB;
        int c2 = lane & 31;
        sA[nl * 136 + 64 + 2 * c2] = (_Float16)o0;
        sA[nl * 136 + 64 + 2 * c2 + 1] = (_Float16)o1;
    }
    __syncthreads();
    const int ln15 = lane & 15, quad = lane >> 4;
    const int mt = wid & 3, ng = wid >> 2;      // ng 0..3
    const int mrow = mt * 16 + ln15;
    f16x8 afr[4];
#pragma unroll
    for (int kc = 0; kc < 4; ++kc)
        afr[kc] = *(const f16x8*)&sA[mrow * 136 + kc * 32 + quad * 8];
    // cand: c1[64][64] = sA @ Wc1t^T (K=128), 1 tile per wave
    const int colc = ng * 16 + ln15;
    f32x4 accc;
    {
        float b = bc1[colc];
        f32x4 a = {b, b, b, b};
#pragma unroll
        for (int kc = 0; kc < 4; ++kc) {
            f16x8 bfr = *(const f16x8*)&Wc1t[(size_t)colc * 128 + kc * 32 + quad * 8];
            a = __builtin_amdgcn_mfma_f32_16x16x32_f16(afr[kc], bfr, a, 0, 0, 0);
        }
        accc = a;
    }
    // gate0(t+1): rz0[64][128] = sX@Wg0t_x + sA(0:64)@Wg0t_h, 2 tiles/wave
    f32x4 accg[2];
    int colg[2];
    if (do_gate) {
        f16x8 xfr = *(const f16x8*)&sX[mrow * 40 + quad * 8];
#pragma unroll
        for (int nt = 0; nt < 2; ++nt) {
            int col = (ng * 2 + nt) * 16 + ln15;
            colg[nt] = col;
            float b = bg0[col];
            f32x4 a = {b, b, b, b};
            f16x8 bx = *(const f16x8*)&Wg0t_x[(size_t)col * 32 + quad * 8];
            a = __builtin_amdgcn_mfma_f32_16x16x32_f16(xfr, bx, a, 0, 0, 0);
#pragma unroll
            for (int kc = 0; kc < 2; ++kc) {
                f16x8 bfr = *(const f16x8*)&Wg0t_h[(size_t)col * 64 + kc * 32 + quad * 8];
                a = __builtin_amdgcn_mfma_f32_16x16x32_f16(afr[kc], bfr, a, 0, 0, 0);
            }
            accg[nt] = a;
        }
    }
    __syncthreads();
    // stage: c1 -> sA cols 64..127; r0 -> sA cols 0..63 (z0 stays in regs)
#pragma unroll
    for (int r = 0; r < 4; ++r) {
        float e = __expf(2.f * accc[r]);
        float c = 1.f - 2.f / (e + 1.f);
        int row = mt * 16 + quad * 4 + r;
        sA[row * 136 + 64 + colc] = (_Float16)c;
    }
    if (do_gate) {
#pragma unroll
        for (int nt = 0; nt < 2; ++nt) {
            if (colg[nt] < 64) {
#pragma unroll
                for (int r = 0; r < 4; ++r) {
                    float s = 1.f / (1.f + __expf(-accg[nt][r]));
                    int row = mt * 16 + quad * 4 + r;
                    sA[row * 136 + colg[nt]] = (_Float16)s;
                }
            }
        }
    }
    __syncthreads();
    // epilogue-1: h1 update (+RH0h, +final out)
    for (int i = tid; i < 4096; i += 1024) {
        int nl = i >> 6, cc = i & 63, n = nb + nl;
        float nh = 0.f;
        if (n < N) {
            size_t idx = (size_t)n * 64 + cc;
            float z1 = (float)Zh[idx];
            float hv = h1f[idx];
            nh = z1 * hv + (1.f - z1) * (float)sA[nl * 136 + 64 + cc];
            if (!final) {
                h1f[idx] = nh;
                reinterpret_cast<__half*>(h01)[idx * 2 + 1] = __float2half(nh);
            }
            if (do_gate) RH0h[idx] = (_Float16)((float)sA[nl * 136 + cc] * h0f[idx]);
        }
        if (final) {
            float p = nh * Wout[cc];
            for (int off = 32; off > 0; off >>= 1) p += __shfl_down(p, off);
            if (cc == 0 && n < N) out[n] = p + bout[0];
        }
    }
    if (do_gate) {
        __syncthreads();
        // stage z0 (gate cols >= 64) -> sA cols 0..63
#pragma unroll
        for (int nt = 0; nt < 2; ++nt) {
            if (colg[nt] >= 64) {
#pragma unroll
                for (int r = 0; r < 4; ++r) {
                    float s = 1.f / (1.f + __expf(-accg[nt][r]));
                    int row = mt * 16 + quad * 4 + r;
                    sA[row * 136 + (colg[nt] - 64)] = (_Float16)s;
                }
            }
        }
        __syncthreads();
        for (int i = tid; i < 4096; i += 1024) {
            int nl = i >> 6, cc = i & 63, n = nb + nl;
            if (n < N) Zh[(size_t)n * 64 + cc] = sA[nl * 136 + cc];
        }
    }
}

static inline size_t align16(size_t v) { return (v + 15) & ~(size_t)15; }

extern "C" void kernel_launch(void* const* d_in, const int* in_sizes, int n_in,
                              void* d_out, int out_size, void* d_ws, size_t ws_size,
                              hipStream_t stream) {
    const float* x   = (const float*)d_in[0];
    const int*   ei  = (const int*)d_in[1];
    const float* ew  = (const float*)d_in[2];
    const float* Wg0 = (const float*)d_in[3];
    const float* bg0 = (const float*)d_in[4];
    const float* Wc0 = (const float*)d_in[5];
    const float* bc0 = (const float*)d_in[6];
    const float* Wg1 = (const float*)d_in[7];
    const float* bg1 = (const float*)d_in[8];
    const float* Wc1 = (const float*)d_in[9];
    const float* bc1 = (const float*)d_in[10];
    const float* Wout = (const float*)d_in[11];
    const float* bout = (const float*)d_in[12];

    const int N = in_sizes[0] / FT;
    const int E = in_sizes[2];
    const int* src = ei;
    const int* dst = ei + E;

    char* base = (char*)d_ws;
    size_t off = 0;
    int* deg = (int*)(base + off);            off = align16(off + (size_t)N * 4);
    int* cursor = (int*)(base + off);         off = align16(off + (size_t)N * 4);
    int* rowptr = (int*)(base + off);         off = align16(off + (size_t)(N + 1) * 4);
    int* part = (int*)(base + off);           off = align16(off + 256 * 4);
    unsigned* csr_ew = (unsigned*)(base + off);  off = align16(off + (size_t)E * 4);
    float* aggXt = (float*)(base + off);      off = align16(off + (size_t)N * FT * 4);
    float* h0f = (float*)(base + off);        off = align16(off + (size_t)N * 64 * 4);
    float* h1f = (float*)(base + off);        off = align16(off + (size_t)N * 64 * 4);
    unsigned* h01 = (unsigned*)(base + off);  off = align16(off + (size_t)N * 64 * 4);
    unsigned* Aglobh32 = (unsigned*)(base + off); off = align16(off + (size_t)N * 32 * 4);
    _Float16* Zh = (_Float16*)(base + off);   off = align16(off + (size_t)N * 64 * 2);
    _Float16* RH0h = (_Float16*)(base + off); off = align16(off + (size_t)N * 64 * 2);
    _Float16* RH1h = (_Float16*)(base + off); off = align16(off + (size_t)N * 64 * 2);
    _Float16* xh = (_Float16*)(base + off);   off = align16(off + (size_t)N * FT * 2);
    _Float16* Wg1t = (_Float16*)(base + off); off = align16(off + 128 * 128 * 2);
    _Float16* Wc1t = (_Float16*)(base + off); off = align16(off + 64 * 128 * 2);
    _Float16* Wc0t = (_Float16*)(base + off); off = align16(off + 64 * 96 * 2);
    _Float16* Wg0t_h = (_Float16*)(base + off); off = align16(off + 128 * 64 * 2);
    _Float16* Wg0t_x = (_Float16*)(base + off); off = align16(off + 128 * 32 * 2);

    const int gE   = (E + 255) / 256;
    const int gN4  = (N + 3) / 4;
    const int gN64 = (N + 63) / 64;
    const int G    = (N + 255) / 256;

    hipMemsetAsync(deg, 0, (size_t)N * 4, stream);
    hipMemsetAsync(h0f, 0, (size_t)N * 64 * 4, stream);
    hipMemsetAsync(h1f, 0, (size_t)N * 64 * 4, stream);
    hipMemsetAsync(h01, 0, (size_t)N * 64 * 4, stream);
    hipMemsetAsync(RH0h, 0, (size_t)N * 64 * 2, stream);

    x2h_k<<<(N * FT + 255) / 256, 256, 0, stream>>>(x, xh, N * FT);
    wprep_k<<<64, 256, 0, stream>>>(Wg0, Wc0, Wg1, Wc1, Wg1t, Wc1t, Wc0t, Wg0t_h, Wg0t_x);
    hist_k<<<gE, 256, 0, stream>>>(dst, deg, E);
    partial_k<<<G, 256, 0, stream>>>(deg, part, N);
    scanpart_k<<<1, 256, 0, stream>>>(part, rowptr, G, N);
    scanchunk_k<<<G, 256, 0, stream>>>(deg, part, rowptr, cursor, N);
    fill_k<<<gE, 256, 0, stream>>>(src, dst, ew, cursor, csr_ew, E);
    gather96_k<<<gN4, 256, 0, stream>>>(xh, rowptr, csr_ew, aggXt, N);

    // t=0: h0=0 -> RH0h=0 (memset); z0 from aggX only
    g0z_k<<<(N * 64 + 255) / 256, 256, 0, stream>>>(aggXt, Wg0, bg0, Zh, N);

    for (int t = 0; t < TSTEPS; ++t) {
        l0_cand<<<gN64, 1024, 0, stream>>>(RH0h, aggXt, t, rowptr, csr_ew,
                                           Wc0t, bc0, Zh, h0f, h01, N);
        l1_gate<<<gN64, 1024, 0, stream>>>(h01, h1f, rowptr, csr_ew,
                                           Wg1t, bg1, Aglobh32, Zh, RH1h, N);
        l1_cand_fused<<<gN64, 1024, 0, stream>>>(RH1h, Aglobh32, aggXt, t + 1,
                                                 (t + 1 < TSTEPS) ? 1 : 0,
                                                 (t + 1 == TSTEPS) ? 1 : 0,
                                                 rowptr, csr_ew,
                                                 Wc1t, bc1, Wg0t_h, Wg0t_x, bg0,
                                                 h0f, Zh, RH0h, h1f, h01,
                                                 Wout, bout, (float*)d_out, N);
    }
}